// Round 5
// baseline (752.152 us; speedup 1.0000x reference)
//
#include <hip/hip_runtime.h>
#include <stdint.h>
#include <math.h>

#define B_ 32
#define V_ 2048
#define E_ 12288
#define M_ (B_*V_)

typedef __bf16 bf16x8 __attribute__((ext_vector_type(8)));
typedef float f32x4 __attribute__((ext_vector_type(4)));

__device__ __forceinline__ float bf2f(unsigned short u){
  union { unsigned int i; float f; } v; v.i = ((unsigned int)u) << 16; return v.f;
}
__device__ __forceinline__ unsigned short f2bf(float f){
  union { float f; unsigned int i; } v; v.f = f;
  unsigned int r = (v.i + 0x7fffu + ((v.i >> 16) & 1u)) >> 16;
  return (unsigned short)r;
}
// async global->LDS, 16B per lane; LDS dest = uniform base + lane*16
__device__ __forceinline__ void gload16(const unsigned short* g, unsigned short* l){
  __builtin_amdgcn_global_load_lds(
      (const __attribute__((address_space(1))) void*)g,
      (__attribute__((address_space(3))) void*)l, 16, 0, 0);
}

// ---------------- CSR build ----------------
__global__ void k_deg(const int* __restrict__ ei, int* __restrict__ deg){
  int e = blockIdx.x * 256 + threadIdx.x;
  if (e < E_) atomicAdd(&deg[ei[E_ + e]], 1);   // dst side
}

__global__ void k_scan(const int* __restrict__ cnt, int* __restrict__ rowptr,
                       float* __restrict__ dinv, float* __restrict__ selfw){
  int lane = threadIdx.x;      // 64 threads
  int base = lane * 32;
  int local[32]; int s = 0;
  #pragma unroll
  for (int i = 0; i < 32; i++){ local[i] = cnt[base + i]; s += local[i]; }
  int pre = s;
  for (int off = 1; off < 64; off <<= 1){
    int t = __shfl_up(pre, off);
    if (lane >= off) pre += t;
  }
  pre -= s;  // exclusive
  int run = pre;
  #pragma unroll
  for (int i = 0; i < 32; i++){
    rowptr[base + i] = run; run += local[i];
    float d = (float)(local[i] + 1);          // + self loop
    float di = rsqrtf(d);
    dinv[base + i] = di;
    selfw[base + i] = di * di;
  }
  if (lane == 63) rowptr[V_] = run;
}

__global__ void k_scatter(const int* __restrict__ ei, const int* __restrict__ rowptr,
                          int* __restrict__ fill, int* __restrict__ cols,
                          float* __restrict__ vals, const float* __restrict__ dinv){
  int e = blockIdx.x * 256 + threadIdx.x;
  if (e < E_){
    int s = ei[e], d = ei[E_ + e];
    int pos = rowptr[d] + atomicAdd(&fill[d], 1);
    cols[pos] = s;
    vals[pos] = dinv[s] * dinv[d];
  }
}

__global__ void k_wsum(const int* __restrict__ rowptr, const float* __restrict__ vals,
                       const float* __restrict__ selfw, float* __restrict__ wsum){
  int v = blockIdx.x * 256 + threadIdx.x;
  if (v < V_){
    float s = selfw[v];
    for (int e = rowptr[v]; e < rowptr[v + 1]; e++) s += vals[e];
    wsum[v] = s;
  }
}

__global__ void k_w2(const int* __restrict__ rowptr, const int* __restrict__ cols,
                     const float* __restrict__ vals, const float* __restrict__ selfw,
                     const float* __restrict__ wsum, float* __restrict__ w2){
  int v = blockIdx.x * 256 + threadIdx.x;
  if (v < V_){
    float s = selfw[v] * wsum[v];
    for (int e = rowptr[v]; e < rowptr[v + 1]; e++) s += vals[e] * wsum[cols[e]];
    w2[v] = s;
  }
}

// ---------------- k_prep: W3 -> bf16 (plain) + W4 -> bf16 transpose ----------------
__global__ void k_prep(const float* __restrict__ W3, const float* __restrict__ W4,
                       unsigned short* __restrict__ W3B, unsigned short* __restrict__ W4T){
  int id = blockIdx.x * 256 + threadIdx.x;
  if (id < 512 * 512){
    W3B[id] = f2bf(W3[id]);
  } else {
    int i = id - 512 * 512;          // W4T[n*512+k] = W4[k*512+n]
    W4T[i] = f2bf(W4[(i & 511) * 512 + (i >> 9)]);
  }
}

// ---------------- k_vmall: C34 = b3@W4 ; W56 = W5@W6 ; C56 = b5@W6 ----------------
__global__ void k_vmall(const float* __restrict__ b3, const float* __restrict__ W4,
                        const float* __restrict__ W5, const float* __restrict__ W6,
                        const float* __restrict__ b5,
                        float* __restrict__ C34, float* __restrict__ W56,
                        float* __restrict__ C56){
  int id = blockIdx.x * 256 + threadIdx.x;
  if (id < 512){
    float acc = 0.f;
    for (int k = 0; k < 512; k++) acc += b3[k] * W4[(size_t)k * 512 + id];
    C34[id] = acc;
  } else if (id < 512 + 512 * 3){
    int i = id - 512; int k5 = i / 3, j = i % 3;
    float acc = 0.f;
    for (int t = 0; t < 64; t++) acc += W5[k5 * 64 + t] * W6[t * 3 + j];
    W56[i] = acc;
  } else if (id < 512 + 512 * 3 + 3){
    int j = id - (512 + 512 * 3);
    float acc = 0.f;
    for (int t = 0; t < 64; t++) acc += b5[t] * W6[t * 3 + j];
    C56[j] = acc;
  }
}

// ---------------- split-K stage A: partial[s][r][n], R rows resident in regs ----------------
template<int R, int KC>
__global__ __launch_bounds__(256) void k_fcp(
    const float* __restrict__ in, const float* __restrict__ W,
    float* __restrict__ partial, int K, int N){
  const int n = blockIdx.x * 256 + threadIdx.x;
  const int k0 = blockIdx.y * KC;
  float acc[R] = {};
  for (int kk = 0; kk < KC; kk += 4){
    const float* wp = W + (size_t)(k0 + kk) * N + n;
    float w0 = wp[0];
    float w1 = wp[(size_t)N];
    float w2 = wp[(size_t)2 * N];
    float w3 = wp[(size_t)3 * N];
    #pragma unroll
    for (int r = 0; r < R; r++){
      const float* xp = in + (size_t)r * K + k0 + kk;
      acc[r] += xp[0] * w0 + xp[1] * w1 + xp[2] * w2 + xp[3] * w3;
    }
  }
  float* p = partial + (size_t)blockIdx.y * R * N + n;
  #pragma unroll
  for (int r = 0; r < R; r++) p[(size_t)r * N] = acc[r];
}

// ---------------- split-K stage B ----------------
__global__ __launch_bounds__(256) void k_fcr(
    const float* __restrict__ partial, const float* __restrict__ bias,
    float* __restrict__ out, int total, int N, int KS, int mode,
    const float* __restrict__ vert){
  int id = blockIdx.x * 256 + threadIdx.x;
  if (id >= total) return;
  int n = id % N;
  float a0 = 0.f, a1 = 0.f, a2 = 0.f, a3 = 0.f;
  int s = 0;
  for (; s + 4 <= KS; s += 4){
    a0 += partial[(size_t)s * total + id];
    a1 += partial[(size_t)(s + 1) * total + id];
    a2 += partial[(size_t)(s + 2) * total + id];
    a3 += partial[(size_t)(s + 3) * total + id];
  }
  for (; s < KS; s++) a0 += partial[(size_t)s * total + id];
  float acc = a0 + a1 + a2 + a3;
  if (bias) acc += bias[n];
  if (mode) acc = vert[id] + 0.1f * tanhf(acc);
  out[id] = acc;
}

// ---------------- CAT = [b1; W1 rows 0-2; I1]  (36 x 512) ----------------
__global__ void k_cat36(const float* __restrict__ b1, const float* __restrict__ W1,
                        const float* __restrict__ I1, float* __restrict__ CAT){
  int id = blockIdx.x * 256 + threadIdx.x;
  if (id >= 36 * 512) return;
  int r = id >> 9, c = id & 511;
  float v;
  if (r == 0)      v = b1[c];
  else if (r < 4)  v = W1[(r - 1) * 512 + c];
  else             v = I1[(r - 4) * 512 + c];
  CAT[id] = v;
}

// ---------------- F=3 fp32 aggregation (thread per b*V+dst) ----------------
__global__ void k_agg3f(const float* __restrict__ h, const int* __restrict__ rowptr,
                        const int* __restrict__ cols, const float* __restrict__ vals,
                        const float* __restrict__ selfw, float* __restrict__ out,
                        const float* __restrict__ cvec, const float* __restrict__ bias,
                        int relu){
  int id = blockIdx.x * 256 + threadIdx.x;   // m = b*V + dst
  int dst = id & (V_ - 1);
  const float* hb = h + (size_t)(id - dst) * 3;   // batch base
  float sw = selfw[dst];
  float a0 = sw * hb[dst * 3], a1 = sw * hb[dst * 3 + 1], a2 = sw * hb[dst * 3 + 2];
  float wsum = sw;
  int rs = rowptr[dst], re = rowptr[dst + 1];
  for (int e = rs; e < re; e++){
    int s = cols[e]; float vv = vals[e]; wsum += vv;
    a0 += vv * hb[s * 3]; a1 += vv * hb[s * 3 + 1]; a2 += vv * hb[s * 3 + 2];
  }
  if (cvec){
    a0 += wsum * cvec[0] + bias[0];
    a1 += wsum * cvec[1] + bias[1];
    a2 += wsum * cvec[2] + bias[2];
  }
  if (relu){ a0 = fmaxf(a0, 0.f); a1 = fmaxf(a1, 0.f); a2 = fmaxf(a2, 0.f); }
  out[(size_t)id * 3] = a0; out[(size_t)id * 3 + 1] = a1; out[(size_t)id * 3 + 2] = a2;
}

// ---------------- x2 build: relu(VA2*Wv + w2*i12 + wsum*c12 + b2) -> bf16, uint4 stores ----------------
__global__ __launch_bounds__(256) void k_x2(
    const float* __restrict__ va2, const float* __restrict__ P,
    const float* __restrict__ wsum, const float* __restrict__ w2s,
    const float* __restrict__ b2, unsigned short* __restrict__ X){
  int m = blockIdx.x * 4 + (threadIdx.x >> 6);
  int b = m >> 11, v = m & (V_ - 1);
  int f = (threadIdx.x & 63) * 8;
  const float* c12 = P;
  const float* wv  = P + 512;
  const float* i12 = P + 4 * 512 + (size_t)b * 512;
  float x0 = va2[(size_t)m * 3], x1 = va2[(size_t)m * 3 + 1], x2v = va2[(size_t)m * 3 + 2];
  float ws = wsum[v], w2 = w2s[v];
  unsigned int o[4];
  #pragma unroll
  for (int i = 0; i < 4; i++){
    int fc = f + 2 * i;
    float r0 = x0 * wv[fc]     + x1 * wv[512 + fc]     + x2v * wv[1024 + fc]
             + w2 * i12[fc]     + ws * c12[fc]     + b2[fc];
    float r1 = x0 * wv[fc + 1] + x1 * wv[512 + fc + 1] + x2v * wv[1024 + fc + 1]
             + w2 * i12[fc + 1] + ws * c12[fc + 1] + b2[fc + 1];
    r0 = fmaxf(r0, 0.f); r1 = fmaxf(r1, 0.f);
    o[i] = (unsigned int)f2bf(r0) | ((unsigned int)f2bf(r1) << 16);
  }
  *(uint4*)&X[(size_t)m * 512 + f] = *(uint4*)o;
}

// ---------------- F=512 bf16 aggregation: block per dst, all 32 batches ----------------
template<int BGRP>
__global__ __launch_bounds__(256) void k_aggb(
    const unsigned short* __restrict__ Hg, const int* __restrict__ rowptr,
    const int* __restrict__ cols, const float* __restrict__ vals,
    const float* __restrict__ selfw, unsigned short* __restrict__ Xo){
  constexpr int NJ = BGRP / 4;
  int dst = blockIdx.x;
  int b = threadIdx.x >> 6;
  int f8 = (threadIdx.x & 63) * 8;
  float sw = selfw[dst];
  int rs = rowptr[dst], re = rowptr[dst + 1];
  float a[NJ][8];
  #pragma unroll
  for (int jj = 0; jj < NJ; jj++){
    uint4 q = *(const uint4*)&Hg[((size_t)(b + jj * 4) * V_ + dst) * 512 + f8];
    const unsigned int* w = (const unsigned int*)&q;
    #pragma unroll
    for (int i = 0; i < 4; i++){
      a[jj][2 * i]     = sw * bf2f(w[i] & 0xffff);
      a[jj][2 * i + 1] = sw * bf2f(w[i] >> 16);
    }
  }
  for (int e = rs; e < re; e++){
    int s = cols[e]; float v = vals[e];
    uint4 q[NJ];
    #pragma unroll
    for (int jj = 0; jj < NJ; jj++)
      q[jj] = *(const uint4*)&Hg[((size_t)(b + jj * 4) * V_ + s) * 512 + f8];
    #pragma unroll
    for (int jj = 0; jj < NJ; jj++){
      const unsigned int* w = (const unsigned int*)&q[jj];
      #pragma unroll
      for (int i = 0; i < 4; i++){
        a[jj][2 * i]     += v * bf2f(w[i] & 0xffff);
        a[jj][2 * i + 1] += v * bf2f(w[i] >> 16);
      }
    }
  }
  #pragma unroll
  for (int jj = 0; jj < NJ; jj++){
    unsigned int o[4];
    #pragma unroll
    for (int i = 0; i < 4; i++)
      o[i] = (unsigned int)f2bf(a[jj][2 * i]) | ((unsigned int)f2bf(a[jj][2 * i + 1]) << 16);
    *(uint4*)&Xo[((size_t)(b + jj * 4) * V_ + dst) * 512 + f8] = *(uint4*)o;
  }
}

// ---------------- bf16 MFMA GEMM v2: A dbuf via global_load_lds, B direct from L2 ----------------
// Hg[M,N] = Xg[M,K] @ Wt^T (Wt is [N][K]); epilogue: += wsumv[row&(V-1)]*cvec[col]+bias[col]; relu opt.
template<int BM, int BN, int WM, int WN, int TM, int TN>
__global__ __launch_bounds__(WM*WN*64) void k_gemm(
    const unsigned short* __restrict__ Xg, const unsigned short* __restrict__ Wt,
    unsigned short* __restrict__ Hg, int K, int N,
    const float* __restrict__ wsumv, const float* __restrict__ cvec,
    const float* __restrict__ bias, int relu){
  constexpr int BK = 32;
  constexpr int NW = WM * WN;
  constexpr int RA = BM / NW;                 // A rows staged per wave (16 per instr)
  __shared__ __align__(16) unsigned short As[2][BM * BK];
  const int tid = threadIdx.x;
  const int row0 = blockIdx.x * BM, col0 = blockIdx.y * BN;
  const int wave = tid >> 6, lane = tid & 63;
  const int wr = wave / WN, wc = wave % WN;
  const int lrow = lane & 15, lq = lane >> 4;
  const int lrw = lane >> 2, lcol = (lane & 3) * 8;   // 16 rows x 32 cols per instr
  const int arow = wave * RA;
  const unsigned short* browp[TN];
  #pragma unroll
  for (int tn = 0; tn < TN; tn++)
    browp[tn] = &Wt[(size_t)(col0 + wc * TN * 16 + tn * 16 + lrow) * K + lq * 8];
  f32x4 acc[TM][TN] = {};
  // prologue: stage k0=0 into buf 0
  #pragma unroll
  for (int t = 0; t < RA / 16; t++)
    gload16(&Xg[(size_t)(row0 + arow + t * 16 + lrw) * K + lcol],
            &As[0][(arow + t * 16) * BK]);
  int cur = 0;
  for (int k0 = 0; k0 < K; k0 += BK){
    __syncthreads();   // vmcnt drain: As[cur] DMA done; all waves done reading As[cur^1]
    if (k0 + BK < K){
      #pragma unroll
      for (int t = 0; t < RA / 16; t++)
        gload16(&Xg[(size_t)(row0 + arow + t * 16 + lrw) * K + k0 + BK + lcol],
                &As[cur ^ 1][(arow + t * 16) * BK]);
    }
    bf16x8 bfr[TN];
    #pragma unroll
    for (int tn = 0; tn < TN; tn++)
      bfr[tn] = *(const bf16x8*)&browp[tn][k0];       // L2-hot weight, no LDS
    bf16x8 af[TM];
    #pragma unroll
    for (int tm = 0; tm < TM; tm++)
      af[tm] = *(const bf16x8*)&As[cur][(wr * TM * 16 + tm * 16 + lrow) * BK + lq * 8];
    #pragma unroll
    for (int tm = 0; tm < TM; tm++)
      #pragma unroll
      for (int tn = 0; tn < TN; tn++)
        acc[tm][tn] = __builtin_amdgcn_mfma_f32_16x16x32_bf16(af[tm], bfr[tn], acc[tm][tn], 0, 0, 0);
    cur ^= 1;
  }
  #pragma unroll
  for (int tm = 0; tm < TM; tm++){
    #pragma unroll
    for (int tn = 0; tn < TN; tn++){
      int col = col0 + wc * TN * 16 + tn * 16 + lrow;
      float cv = 0.f, bv = 0.f;
      if (cvec){ cv = cvec[col]; bv = bias[col]; }
      #pragma unroll
      for (int r = 0; r < 4; r++){
        int row = row0 + wr * TM * 16 + tm * 16 + lq * 4 + r;
        float x = acc[tm][tn][r];
        if (cvec) x += wsumv[row & (V_ - 1)] * cv + bv;
        if (relu) x = fmaxf(x, 0.f);
        Hg[(size_t)row * N + col] = f2bf(x);
      }
    }
  }
}

// ---------------- h5 = x4 @ W56  (K=512, N=3): wave per row, coalesced + shuffle reduce ----------------
__global__ __launch_bounds__(256) void k_h5(
    const unsigned short* __restrict__ x4, const float* __restrict__ W56,
    float* __restrict__ h5){
  int m = blockIdx.x * 4 + (threadIdx.x >> 6);
  int lane = threadIdx.x & 63;
  uint4 q = *(const uint4*)&x4[(size_t)m * 512 + lane * 8];
  const unsigned int* w = (const unsigned int*)&q;
  float a0 = 0.f, a1 = 0.f, a2 = 0.f;
  #pragma unroll
  for (int i = 0; i < 8; i++){
    float x = bf2f((i & 1) ? (unsigned short)(w[i >> 1] >> 16)
                           : (unsigned short)(w[i >> 1] & 0xffff));
    int k = lane * 8 + i;
    a0 += x * W56[k * 3]; a1 += x * W56[k * 3 + 1]; a2 += x * W56[k * 3 + 2];
  }
  #pragma unroll
  for (int off = 32; off; off >>= 1){
    a0 += __shfl_down(a0, off);
    a1 += __shfl_down(a1, off);
    a2 += __shfl_down(a2, off);
  }
  if (lane == 0){
    h5[(size_t)m * 3] = a0; h5[(size_t)m * 3 + 1] = a1; h5[(size_t)m * 3 + 2] = a2;
  }
}

// ---------------- workspace layout ----------------
static constexpr size_t AL(size_t x){ return (x + 255) & ~(size_t)255; }
static constexpr size_t S512 = (size_t)M_ * 512 * 2;   // 64 MiB bf16 buffer
static constexpr size_t S3   = (size_t)M_ * 3 * 4;
static constexpr size_t OXA  = 0;                       // X buffer A / FC-head partials
static constexpr size_t OXB  = OXA  + AL(S512);         // X buffer B / precompute partials
static constexpr size_t OVA1 = OXB  + AL(S512);
static constexpr size_t OVA2 = OVA1 + AL(S3);
static constexpr size_t OH5  = OVA2 + AL(S3);
static constexpr size_t OH6  = OH5  + AL(S3);
static constexpr size_t OXF  = OH6  + AL(S3);
static constexpr size_t OFC1 = OXF  + AL(S3);
static constexpr size_t OFC2 = OFC1 + AL((size_t)B_ * 1024 * 4);
static constexpr size_t OI1  = OFC2 + AL((size_t)B_ * 1024 * 4);
static constexpr size_t OCAT = OI1  + AL((size_t)32 * 512 * 4);
static constexpr size_t OP   = OCAT + AL((size_t)36 * 512 * 4);
static constexpr size_t OC34 = OP   + AL((size_t)36 * 512 * 4);
static constexpr size_t OW56 = OC34 + AL((size_t)512 * 4);
static constexpr size_t OC56 = OW56 + AL((size_t)512 * 3 * 4);
static constexpr size_t OW3B = OC56 + AL((size_t)3 * 4);
static constexpr size_t OW4T = OW3B + AL((size_t)512 * 512 * 2);
static constexpr size_t OW34 = OW4T + AL((size_t)512 * 512 * 2);
static constexpr size_t ODEG = OW34 + AL((size_t)512 * 512 * 2);
static constexpr size_t OCNT = ODEG + AL((size_t)V_ * 4);
static constexpr size_t OROW = OCNT + AL((size_t)V_ * 4);
static constexpr size_t OCOL = OROW + AL((size_t)(V_ + 1) * 4);
static constexpr size_t OVAL = OCOL + AL((size_t)E_ * 4);
static constexpr size_t OSELF= OVAL + AL((size_t)E_ * 4);
static constexpr size_t ODINV= OSELF+ AL((size_t)V_ * 4);
static constexpr size_t OWS  = ODINV+ AL((size_t)V_ * 4);
static constexpr size_t OW2S = OWS  + AL((size_t)V_ * 4);

extern "C" void kernel_launch(void* const* d_in, const int* in_sizes, int n_in,
                              void* d_out, int out_size, void* d_ws, size_t ws_size,
                              hipStream_t stream){
  const float* vert  = (const float*)d_in[0];
  const float* img   = (const float*)d_in[1];
  const int*   ei    = (const int*)  d_in[2];
  const float* W1 = (const float*)d_in[3],  *b1 = (const float*)d_in[4];
  const float* W2 = (const float*)d_in[5],  *b2 = (const float*)d_in[6];
  const float* W3 = (const float*)d_in[7],  *b3 = (const float*)d_in[8];
  const float* W4 = (const float*)d_in[9],  *b4 = (const float*)d_in[10];
  const float* W5 = (const float*)d_in[11], *b5 = (const float*)d_in[12];
  const float* W6 = (const float*)d_in[13], *b6 = (const float*)d_in[14];
  const float* fcW1 = (const float*)d_in[15], *fcb1 = (const float*)d_in[16];
  const float* fcW2 = (const float*)d_in[17], *fcb2 = (const float*)d_in[18];
  const float* fcW3 = (const float*)d_in[19], *fcb3 = (const float*)d_in[20];
  float* out = (float*)d_out;

  char* ws = (char*)d_ws;
  unsigned short* XA  = (unsigned short*)(ws + OXA);
  unsigned short* XB  = (unsigned short*)(ws + OXB);
  float* VA1  = (float*)(ws + OVA1);
  float* VA2  = (float*)(ws + OVA2);
  float* H5   = (float*)(ws + OH5);
  float* H6   = (float*)(ws + OH6);
  float* XF   = (float*)(ws + OXF);
  float* FC1o = (float*)(ws + OFC1);
  float* FC2o = (float*)(ws + OFC2);
  float* I1   = (float*)(ws + OI1);
  float* CAT  = (float*)(ws + OCAT);
  float* P    = (float*)(ws + OP);
  float* C34  = (float*)(ws + OC34);
  float* W56  = (float*)(ws + OW56);
  float* C56  = (float*)(ws + OC56);
  unsigned short* W3B = (unsigned short*)(ws + OW3B);
  unsigned short* W4T = (unsigned short*)(ws + OW4T);
  unsigned short* W34 = (unsigned short*)(ws + OW34);
  float* PARTA = (float*)(ws + OXA);   // FC-head partials (XA free then)
  float* PARTB = (float*)(ws + OXB);   // precompute partials (XB free then)
  int*   DEG  = (int*)(ws + ODEG);
  int*   CNT  = (int*)(ws + OCNT);
  int*   ROW  = (int*)(ws + OROW);
  int*   COL  = (int*)(ws + OCOL);
  float* VAL  = (float*)(ws + OVAL);
  float* SELF = (float*)(ws + OSELF);
  float* DINV = (float*)(ws + ODINV);
  float* WSUM = (float*)(ws + OWS);
  float* W2S  = (float*)(ws + OW2S);

  // ---- CSR + norm powers ----
  hipMemsetAsync(ws + ODEG, 0, OROW - ODEG, stream);
  k_deg<<<(E_ + 255) / 256, 256, 0, stream>>>(ei, DEG);
  k_scan<<<1, 64, 0, stream>>>(DEG, ROW, DINV, SELF);
  k_scatter<<<(E_ + 255) / 256, 256, 0, stream>>>(ei, ROW, CNT, COL, VAL, DINV);
  k_wsum<<<(V_ + 255) / 256, 256, 0, stream>>>(ROW, VAL, SELF, WSUM);
  k_w2<<<(V_ + 255) / 256, 256, 0, stream>>>(ROW, COL, VAL, SELF, WSUM, W2S);

  // ---- weight precompute ----
  k_prep<<<(2 * 512 * 512) / 256, 256, 0, stream>>>(W3, W4, W3B, W4T);
  // W34T[n4][k3] = sum_k W4T[n4,k] * W3[k3,k]  (64x64 tiles, 64 blocks)
  k_gemm<64,64,2,2,2,2><<<dim3(8, 8), 256, 0, stream>>>(W4T, W3B, W34, 512, 512,
                                                        nullptr, nullptr, nullptr, 0);
  // I1 = img @ W1[3:,:]
  k_fcp<32,64><<<dim3(2, 8), 256, 0, stream>>>(img, W1 + 3 * 512, PARTB, 512, 512);
  k_fcr<<<(32 * 512 + 255) / 256, 256, 0, stream>>>(PARTB, nullptr, I1, 32 * 512, 512, 8, 0, nullptr);
  // P = [b1; W1[0:3]; I1] @ W2
  k_cat36<<<(36 * 512 + 255) / 256, 256, 0, stream>>>(b1, W1, I1, CAT);
  k_fcp<36,64><<<dim3(2, 8), 256, 0, stream>>>(CAT, W2, PARTB, 512, 512);
  k_fcr<<<(36 * 512 + 255) / 256, 256, 0, stream>>>(PARTB, nullptr, P, 36 * 512, 512, 8, 0, nullptr);
  // C34 / W56 / C56
  k_vmall<<<(512 + 1536 + 3 + 255) / 256, 256, 0, stream>>>(b3, W4, W5, W6, b5, C34, W56, C56);

  // ---- layers 1+2 ----
  k_agg3f<<<M_ / 256, 256, 0, stream>>>(vert, ROW, COL, VAL, SELF, VA1, nullptr, nullptr, 0);
  k_agg3f<<<M_ / 256, 256, 0, stream>>>(VA1, ROW, COL, VAL, SELF, VA2, nullptr, nullptr, 0);
  k_x2<<<M_ / 4, 256, 0, stream>>>(VA2, P, WSUM, W2S, b2, XA);

  // ---- layers 3+4 ----
  k_aggb<32><<<dim3(V_, 1), 256, 0, stream>>>(XA, ROW, COL, VAL, SELF, XB);
  k_aggb<32><<<dim3(V_, 1), 256, 0, stream>>>(XB, ROW, COL, VAL, SELF, XA);
  k_gemm<128,128,2,2,4,4><<<dim3(M_ / 128, 4), 256, 0, stream>>>(XA, W34, XB, 512, 512,
                                                                 WSUM, C34, b4, 1);

  // ---- layers 5+6 ----
  k_h5<<<M_ / 4, 256, 0, stream>>>(XB, W56, H5);
  k_agg3f<<<M_ / 256, 256, 0, stream>>>(H5, ROW, COL, VAL, SELF, H6, nullptr, nullptr, 0);
  k_agg3f<<<M_ / 256, 256, 0, stream>>>(H6, ROW, COL, VAL, SELF, XF, C56, b6, 1);

  // ---- FC head ----
  k_fcp<32,64><<<dim3(4, 96), 256, 0, stream>>>(XF, fcW1, PARTA, 6144, 1024);
  k_fcr<<<(B_ * 1024 + 255) / 256, 256, 0, stream>>>(PARTA, fcb1, FC1o, 32 * 1024, 1024, 96, 0, nullptr);
  k_fcp<32,64><<<dim3(4, 16), 256, 0, stream>>>(FC1o, fcW2, PARTA, 1024, 1024);
  k_fcr<<<(B_ * 1024 + 255) / 256, 256, 0, stream>>>(PARTA, fcb2, FC2o, 32 * 1024, 1024, 16, 0, nullptr);
  k_fcp<32,64><<<dim3(24, 16), 256, 0, stream>>>(FC2o, fcW3, PARTA, 1024, 6144);
  k_fcr<<<(B_ * 6144 + 255) / 256, 256, 0, stream>>>(PARTA, fcb3, out, 32 * 6144, 6144, 16, 1, vert);
}

// Round 6
// 745.646 us; speedup vs baseline: 1.0087x; 1.0087x over previous
//
#include <hip/hip_runtime.h>
#include <stdint.h>
#include <math.h>

#define B_ 32
#define V_ 2048
#define E_ 12288
#define M_ (B_*V_)

typedef __bf16 bf16x8 __attribute__((ext_vector_type(8)));
typedef float f32x4 __attribute__((ext_vector_type(4)));

__device__ __forceinline__ float bf2f(unsigned short u){
  union { unsigned int i; float f; } v; v.i = ((unsigned int)u) << 16; return v.f;
}
__device__ __forceinline__ unsigned short f2bf(float f){
  union { float f; unsigned int i; } v; v.f = f;
  unsigned int r = (v.i + 0x7fffu + ((v.i >> 16) & 1u)) >> 16;
  return (unsigned short)r;
}
// async global->LDS, 16B per lane; LDS dest = uniform base + lane*16
__device__ __forceinline__ void gload16(const unsigned short* g, unsigned short* l){
  __builtin_amdgcn_global_load_lds(
      (const __attribute__((address_space(1))) void*)g,
      (__attribute__((address_space(3))) void*)l, 16, 0, 0);
}

// ---------------- one-shot CSR + norm powers, single block, all in LDS ----------------
__global__ __launch_bounds__(1024) void k_csr(
    const int* __restrict__ ei, int* __restrict__ rowptr_g, int* __restrict__ cols_g,
    float* __restrict__ vals_g, float* __restrict__ selfw_g,
    float* __restrict__ wsum_g, float* __restrict__ w2_g){
  __shared__ int   sdeg[V_];
  __shared__ int   srp[V_ + 1];
  __shared__ int   sfill[V_];
  __shared__ float sdinv[V_];
  __shared__ float swsum[V_];
  __shared__ float sw2[V_];
  __shared__ int   swt[16];
  const int t = threadIdx.x;
  // P1: zero
  sdeg[2*t] = 0; sdeg[2*t+1] = 0; sfill[2*t] = 0; sfill[2*t+1] = 0;
  __syncthreads();
  // P2: degree (dst side)
  #pragma unroll
  for (int e = t; e < E_; e += 1024) atomicAdd(&sdeg[ei[E_ + e]], 1);
  __syncthreads();
  // P3: scan (2 elems/thread)
  int c0 = sdeg[2*t], c1 = sdeg[2*t+1];
  int s2 = c0 + c1;
  int lane = t & 63, wid = t >> 6;
  int pre = s2;
  #pragma unroll
  for (int off = 1; off < 64; off <<= 1){
    int u = __shfl_up(pre, off);
    if (lane >= off) pre += u;
  }
  if (lane == 63) swt[wid] = pre;
  __syncthreads();
  if (t == 0){
    int run = 0;
    #pragma unroll
    for (int i = 0; i < 16; i++){ int x = swt[i]; swt[i] = run; run += x; }
    srp[V_] = run;
  }
  __syncthreads();
  int base = swt[wid] + (pre - s2);
  srp[2*t] = base; srp[2*t+1] = base + c0;
  // P4: dinv / selfw / wsum init
  #pragma unroll
  for (int v = t; v < V_; v += 1024){
    float d = (float)(sdeg[v] + 1);
    float di = rsqrtf(d);
    sdinv[v] = di;
    swsum[v] = di * di;        // selfw contribution
  }
  __syncthreads();
  // P5: scatter edges + accumulate wsum
  #pragma unroll
  for (int e = t; e < E_; e += 1024){
    int s = ei[e], d = ei[E_ + e];
    int pos = srp[d] + atomicAdd(&sfill[d], 1);
    float val = sdinv[s] * sdinv[d];
    cols_g[pos] = s;
    vals_g[pos] = val;
    atomicAdd(&swsum[d], val);
  }
  __syncthreads();
  // P6: w2 init with self term
  #pragma unroll
  for (int v = t; v < V_; v += 1024)
    sw2[v] = (sdinv[v] * sdinv[v]) * swsum[v];
  __syncthreads();
  // P7: w2 edge contributions
  #pragma unroll
  for (int e = t; e < E_; e += 1024){
    int s = ei[e], d = ei[E_ + e];
    atomicAdd(&sw2[d], sdinv[s] * sdinv[d] * swsum[s]);
  }
  __syncthreads();
  // P8: write out
  #pragma unroll
  for (int v = t; v < V_; v += 1024){
    rowptr_g[v] = srp[v];
    selfw_g[v]  = sdinv[v] * sdinv[v];
    wsum_g[v]   = swsum[v];
    w2_g[v]     = sw2[v];
  }
  if (t == 0) rowptr_g[V_] = srp[V_];
}

// ---------------- k_prep: W3 -> bf16 (plain) + W4 -> bf16 transpose ----------------
__global__ void k_prep(const float* __restrict__ W3, const float* __restrict__ W4,
                       unsigned short* __restrict__ W3B, unsigned short* __restrict__ W4T){
  int id = blockIdx.x * 256 + threadIdx.x;
  if (id < 512 * 512){
    W3B[id] = f2bf(W3[id]);
  } else {
    int i = id - 512 * 512;          // W4T[n*512+k] = W4[k*512+n]
    W4T[i] = f2bf(W4[(i & 511) * 512 + (i >> 9)]);
  }
}

// ---------------- k_vmall: C34 = b3@W4 ; W56 = W5@W6 ; C56 = b5@W6 ----------------
__global__ void k_vmall(const float* __restrict__ b3, const float* __restrict__ W4,
                        const float* __restrict__ W5, const float* __restrict__ W6,
                        const float* __restrict__ b5,
                        float* __restrict__ C34, float* __restrict__ W56,
                        float* __restrict__ C56){
  int id = blockIdx.x * 256 + threadIdx.x;
  if (id < 512){
    float acc = 0.f;
    for (int k = 0; k < 512; k++) acc += b3[k] * W4[(size_t)k * 512 + id];
    C34[id] = acc;
  } else if (id < 512 + 512 * 3){
    int i = id - 512; int k5 = i / 3, j = i % 3;
    float acc = 0.f;
    for (int t = 0; t < 64; t++) acc += W5[k5 * 64 + t] * W6[t * 3 + j];
    W56[i] = acc;
  } else if (id < 512 + 512 * 3 + 3){
    int j = id - (512 + 512 * 3);
    float acc = 0.f;
    for (int t = 0; t < 64; t++) acc += b5[t] * W6[t * 3 + j];
    C56[j] = acc;
  }
}

// ---------------- split-K stage A: partial[s][r][n], R rows resident in regs ----------------
template<int R, int KC>
__global__ __launch_bounds__(256) void k_fcp(
    const float* __restrict__ in, const float* __restrict__ W,
    float* __restrict__ partial, int K, int N){
  const int n = blockIdx.x * 256 + threadIdx.x;
  const int k0 = blockIdx.y * KC;
  float acc[R] = {};
  for (int kk = 0; kk < KC; kk += 4){
    const float* wp = W + (size_t)(k0 + kk) * N + n;
    float w0 = wp[0];
    float w1 = wp[(size_t)N];
    float w2 = wp[(size_t)2 * N];
    float w3 = wp[(size_t)3 * N];
    #pragma unroll
    for (int r = 0; r < R; r++){
      const float* xp = in + (size_t)r * K + k0 + kk;
      acc[r] += xp[0] * w0 + xp[1] * w1 + xp[2] * w2 + xp[3] * w3;
    }
  }
  float* p = partial + (size_t)blockIdx.y * R * N + n;
  #pragma unroll
  for (int r = 0; r < R; r++) p[(size_t)r * N] = acc[r];
}

// ---------------- split-K stage B ----------------
__global__ __launch_bounds__(256) void k_fcr(
    const float* __restrict__ partial, const float* __restrict__ bias,
    float* __restrict__ out, int total, int N, int KS, int mode,
    const float* __restrict__ vert){
  int id = blockIdx.x * 256 + threadIdx.x;
  if (id >= total) return;
  int n = id % N;
  float a0 = 0.f, a1 = 0.f, a2 = 0.f, a3 = 0.f;
  int s = 0;
  for (; s + 4 <= KS; s += 4){
    a0 += partial[(size_t)s * total + id];
    a1 += partial[(size_t)(s + 1) * total + id];
    a2 += partial[(size_t)(s + 2) * total + id];
    a3 += partial[(size_t)(s + 3) * total + id];
  }
  for (; s < KS; s++) a0 += partial[(size_t)s * total + id];
  float acc = a0 + a1 + a2 + a3;
  if (bias) acc += bias[n];
  if (mode) acc = vert[id] + 0.1f * tanhf(acc);
  out[id] = acc;
}

// ---------------- CAT = [b1; W1 rows 0-2; I1]  (36 x 512) ----------------
__global__ void k_cat36(const float* __restrict__ b1, const float* __restrict__ W1,
                        const float* __restrict__ I1, float* __restrict__ CAT){
  int id = blockIdx.x * 256 + threadIdx.x;
  if (id >= 36 * 512) return;
  int r = id >> 9, c = id & 511;
  float v;
  if (r == 0)      v = b1[c];
  else if (r < 4)  v = W1[(r - 1) * 512 + c];
  else             v = I1[(r - 4) * 512 + c];
  CAT[id] = v;
}

// ---------------- fused A^2 for F=3: block per batch, both hops in LDS ----------------
__global__ __launch_bounds__(1024) void k_agg3x2(
    const float* __restrict__ in, const int* __restrict__ rowptr,
    const int* __restrict__ cols, const float* __restrict__ vals,
    const float* __restrict__ selfw, const float* __restrict__ wsum,
    const float* __restrict__ cvec, const float* __restrict__ bias,
    int relu, float* __restrict__ out){
  __shared__ float xs[V_ * 3];
  __shared__ float ys[V_ * 3];
  int b = blockIdx.x, t = threadIdx.x;
  const float* ib = in + (size_t)b * V_ * 3;
  for (int i = t; i < V_ * 3; i += 1024) xs[i] = ib[i];
  __syncthreads();
  for (int v = t; v < V_; v += 1024){
    float sw = selfw[v];
    float a0 = sw * xs[v * 3], a1 = sw * xs[v * 3 + 1], a2 = sw * xs[v * 3 + 2];
    int re = rowptr[v + 1];
    for (int e = rowptr[v]; e < re; e++){
      int s = cols[e]; float vv = vals[e];
      a0 += vv * xs[s * 3]; a1 += vv * xs[s * 3 + 1]; a2 += vv * xs[s * 3 + 2];
    }
    ys[v * 3] = a0; ys[v * 3 + 1] = a1; ys[v * 3 + 2] = a2;
  }
  __syncthreads();
  float* ob = out + (size_t)b * V_ * 3;
  for (int v = t; v < V_; v += 1024){
    float sw = selfw[v];
    float a0 = sw * ys[v * 3], a1 = sw * ys[v * 3 + 1], a2 = sw * ys[v * 3 + 2];
    int re = rowptr[v + 1];
    for (int e = rowptr[v]; e < re; e++){
      int s = cols[e]; float vv = vals[e];
      a0 += vv * ys[s * 3]; a1 += vv * ys[s * 3 + 1]; a2 += vv * ys[s * 3 + 2];
    }
    if (cvec){
      float w = wsum[v];
      a0 += w * cvec[0] + bias[0];
      a1 += w * cvec[1] + bias[1];
      a2 += w * cvec[2] + bias[2];
    }
    if (relu){ a0 = fmaxf(a0, 0.f); a1 = fmaxf(a1, 0.f); a2 = fmaxf(a2, 0.f); }
    ob[v * 3] = a0; ob[v * 3 + 1] = a1; ob[v * 3 + 2] = a2;
  }
}

// ---------------- x2 build -> bf16, VERTEX-MAJOR X[v][b][f], uint4 stores ----------------
__global__ __launch_bounds__(256) void k_x2(
    const float* __restrict__ va2, const float* __restrict__ P,
    const float* __restrict__ wsum, const float* __restrict__ w2s,
    const float* __restrict__ b2, unsigned short* __restrict__ X){
  int m = blockIdx.x * 4 + (threadIdx.x >> 6);   // vertex-major: m = v*32+b
  int v = m >> 5, b = m & 31;
  int f = (threadIdx.x & 63) * 8;
  const float* c12 = P;
  const float* wv  = P + 512;
  const float* i12 = P + 4 * 512 + (size_t)b * 512;
  const float* va  = va2 + ((size_t)b * V_ + v) * 3;     // VA2 is batch-major
  float x0 = va[0], x1 = va[1], x2v = va[2];
  float ws = wsum[v], w2 = w2s[v];
  unsigned int o[4];
  #pragma unroll
  for (int i = 0; i < 4; i++){
    int fc = f + 2 * i;
    float r0 = x0 * wv[fc]     + x1 * wv[512 + fc]     + x2v * wv[1024 + fc]
             + w2 * i12[fc]     + ws * c12[fc]     + b2[fc];
    float r1 = x0 * wv[fc + 1] + x1 * wv[512 + fc + 1] + x2v * wv[1024 + fc + 1]
             + w2 * i12[fc + 1] + ws * c12[fc + 1] + b2[fc + 1];
    r0 = fmaxf(r0, 0.f); r1 = fmaxf(r1, 0.f);
    o[i] = (unsigned int)f2bf(r0) | ((unsigned int)f2bf(r1) << 16);
  }
  *(uint4*)&X[(size_t)m * 512 + f] = *(uint4*)o;
}

// ---------------- F=512 bf16 aggregation, vertex-major: per edge one 32KB contiguous block ----------------
template<int NJ>   // batches per wave; NJ*4 = 32
__global__ __launch_bounds__(256) void k_aggb(
    const unsigned short* __restrict__ Hg, const int* __restrict__ rowptr,
    const int* __restrict__ cols, const float* __restrict__ vals,
    const float* __restrict__ selfw, unsigned short* __restrict__ Xo){
  __shared__ int   sc[64];
  __shared__ float sv[64];
  int dst = blockIdx.x;
  int bw = threadIdx.x >> 6;
  int f8 = (threadIdx.x & 63) * 8;
  int rs = rowptr[dst], re = rowptr[dst + 1];
  int dg = re - rs;
  int t = threadIdx.x;
  if (t < dg && t < 64){ sc[t] = cols[rs + t]; sv[t] = vals[rs + t]; }
  __syncthreads();
  float sw = selfw[dst];
  float a[NJ][8];
  #pragma unroll
  for (int jj = 0; jj < NJ; jj++){
    uint4 q = *(const uint4*)&Hg[((size_t)dst * 32 + bw + jj * 4) * 512 + f8];
    const unsigned int* w = (const unsigned int*)&q;
    #pragma unroll
    for (int i = 0; i < 4; i++){
      a[jj][2 * i]     = sw * bf2f(w[i] & 0xffff);
      a[jj][2 * i + 1] = sw * bf2f(w[i] >> 16);
    }
  }
  for (int e = 0; e < dg; e++){
    int s   = (e < 64) ? sc[e] : cols[rs + e];
    float v = (e < 64) ? sv[e] : vals[rs + e];
    uint4 q[NJ];
    #pragma unroll
    for (int jj = 0; jj < NJ; jj++)
      q[jj] = *(const uint4*)&Hg[((size_t)s * 32 + bw + jj * 4) * 512 + f8];
    #pragma unroll
    for (int jj = 0; jj < NJ; jj++){
      const unsigned int* w = (const unsigned int*)&q[jj];
      #pragma unroll
      for (int i = 0; i < 4; i++){
        a[jj][2 * i]     += v * bf2f(w[i] & 0xffff);
        a[jj][2 * i + 1] += v * bf2f(w[i] >> 16);
      }
    }
  }
  #pragma unroll
  for (int jj = 0; jj < NJ; jj++){
    unsigned int o[4];
    #pragma unroll
    for (int i = 0; i < 4; i++)
      o[i] = (unsigned int)f2bf(a[jj][2 * i]) | ((unsigned int)f2bf(a[jj][2 * i + 1]) << 16);
    *(uint4*)&Xo[((size_t)dst * 32 + bw + jj * 4) * 512 + f8] = *(uint4*)o;
  }
}

// ---------------- bf16 MFMA GEMM v3: A AND B double-buffered via global_load_lds, 1 barrier/iter ----------------
// Hg[M,N] = Xg[M,K] @ Wt^T (Wt is [N][K]); epilogue: += wsumv[row>>5]*cvec[col]+bias[col]; relu opt.
// (rows are vertex-major m = v*32+b when cvec is used)
template<int BM, int BN, int WM, int WN, int TM, int TN>
__global__ __launch_bounds__(WM*WN*64) void k_gemm(
    const unsigned short* __restrict__ Xg, const unsigned short* __restrict__ Wt,
    unsigned short* __restrict__ Hg, int K, int N,
    const float* __restrict__ wsumv, const float* __restrict__ cvec,
    const float* __restrict__ bias, int relu){
  constexpr int BK = 32;
  constexpr int NW = WM * WN;
  constexpr int RA = BM / NW;                 // A rows staged per wave
  constexpr int RB = BN / NW;
  __shared__ __align__(16) unsigned short As[2][BM * BK];
  __shared__ __align__(16) unsigned short Bs[2][BN * BK];
  const int tid = threadIdx.x;
  const int row0 = blockIdx.x * BM, col0 = blockIdx.y * BN;
  const int wave = tid >> 6, lane = tid & 63;
  const int wr = wave / WN, wc = wave % WN;
  const int lrow = lane & 15, lq = lane >> 4;
  const int lrw = lane >> 2, lcol = (lane & 3) * 8;   // 16 rows x 32 cols per instr
  const int arow = wave * RA, brow = wave * RB;
  f32x4 acc[TM][TN] = {};
  // prologue: stage k0=0 into buf 0
  #pragma unroll
  for (int t = 0; t < RA / 16; t++)
    gload16(&Xg[(size_t)(row0 + arow + t * 16 + lrw) * K + lcol],
            &As[0][(arow + t * 16) * BK]);
  #pragma unroll
  for (int t = 0; t < RB / 16; t++)
    gload16(&Wt[(size_t)(col0 + brow + t * 16 + lrw) * K + lcol],
            &Bs[0][(brow + t * 16) * BK]);
  int cur = 0;
  for (int k0 = 0; k0 < K; k0 += BK){
    __syncthreads();   // drains each wave's DMA (buf[cur] ready); prior reads of buf[cur^1] done
    if (k0 + BK < K){
      #pragma unroll
      for (int t = 0; t < RA / 16; t++)
        gload16(&Xg[(size_t)(row0 + arow + t * 16 + lrw) * K + k0 + BK + lcol],
                &As[cur ^ 1][(arow + t * 16) * BK]);
      #pragma unroll
      for (int t = 0; t < RB / 16; t++)
        gload16(&Wt[(size_t)(col0 + brow + t * 16 + lrw) * K + k0 + BK + lcol],
                &Bs[cur ^ 1][(brow + t * 16) * BK]);
    }
    bf16x8 af[TM], bfr[TN];
    #pragma unroll
    for (int tm = 0; tm < TM; tm++)
      af[tm] = *(const bf16x8*)&As[cur][(wr * TM * 16 + tm * 16 + lrow) * BK + lq * 8];
    #pragma unroll
    for (int tn = 0; tn < TN; tn++)
      bfr[tn] = *(const bf16x8*)&Bs[cur][(wc * TN * 16 + tn * 16 + lrow) * BK + lq * 8];
    #pragma unroll
    for (int tm = 0; tm < TM; tm++)
      #pragma unroll
      for (int tn = 0; tn < TN; tn++)
        acc[tm][tn] = __builtin_amdgcn_mfma_f32_16x16x32_bf16(af[tm], bfr[tn], acc[tm][tn], 0, 0, 0);
    cur ^= 1;
  }
  #pragma unroll
  for (int tm = 0; tm < TM; tm++){
    #pragma unroll
    for (int tn = 0; tn < TN; tn++){
      int col = col0 + wc * TN * 16 + tn * 16 + lrow;
      float cv = 0.f, bv = 0.f;
      if (cvec){ cv = cvec[col]; bv = bias[col]; }
      #pragma unroll
      for (int r = 0; r < 4; r++){
        int row = row0 + wr * TM * 16 + tm * 16 + lq * 4 + r;
        float x = acc[tm][tn][r];
        if (cvec) x += wsumv[row >> 5] * cv + bv;   // vertex-major rows
        if (relu) x = fmaxf(x, 0.f);
        Hg[(size_t)row * N + col] = f2bf(x);
      }
    }
  }
}

// ---------------- h5 = x4 @ W56 (K=512,N=3): wave/row, vertex-major in, batch-major out ----------------
__global__ __launch_bounds__(256) void k_h5(
    const unsigned short* __restrict__ x4, const float* __restrict__ W56,
    float* __restrict__ h5){
  int m = blockIdx.x * 4 + (threadIdx.x >> 6);   // vertex-major row
  int lane = threadIdx.x & 63;
  uint4 q = *(const uint4*)&x4[(size_t)m * 512 + lane * 8];
  const unsigned int* w = (const unsigned int*)&q;
  float a0 = 0.f, a1 = 0.f, a2 = 0.f;
  #pragma unroll
  for (int i = 0; i < 8; i++){
    float x = bf2f((i & 1) ? (unsigned short)(w[i >> 1] >> 16)
                           : (unsigned short)(w[i >> 1] & 0xffff));
    int k = lane * 8 + i;
    a0 += x * W56[k * 3]; a1 += x * W56[k * 3 + 1]; a2 += x * W56[k * 3 + 2];
  }
  #pragma unroll
  for (int off = 32; off; off >>= 1){
    a0 += __shfl_down(a0, off);
    a1 += __shfl_down(a1, off);
    a2 += __shfl_down(a2, off);
  }
  if (lane == 0){
    int v = m >> 5, b = m & 31;
    float* o = h5 + ((size_t)b * V_ + v) * 3;    // batch-major out
    o[0] = a0; o[1] = a1; o[2] = a2;
  }
}

// ---------------- workspace layout ----------------
static constexpr size_t AL(size_t x){ return (x + 255) & ~(size_t)255; }
static constexpr size_t S512 = (size_t)M_ * 512 * 2;   // 64 MiB bf16 buffer
static constexpr size_t S3   = (size_t)M_ * 3 * 4;
static constexpr size_t OXA  = 0;                       // X buffer A / FC-head partials
static constexpr size_t OXB  = OXA  + AL(S512);         // X buffer B / precompute partials
static constexpr size_t OVA2 = OXB  + AL(S512);
static constexpr size_t OH5  = OVA2 + AL(S3);
static constexpr size_t OXF  = OH5  + AL(S3);
static constexpr size_t OFC1 = OXF  + AL(S3);
static constexpr size_t OFC2 = OFC1 + AL((size_t)B_ * 1024 * 4);
static constexpr size_t OI1  = OFC2 + AL((size_t)B_ * 1024 * 4);
static constexpr size_t OCAT = OI1  + AL((size_t)32 * 512 * 4);
static constexpr size_t OP   = OCAT + AL((size_t)36 * 512 * 4);
static constexpr size_t OC34 = OP   + AL((size_t)36 * 512 * 4);
static constexpr size_t OW56 = OC34 + AL((size_t)512 * 4);
static constexpr size_t OC56 = OW56 + AL((size_t)512 * 3 * 4);
static constexpr size_t OW3B = OC56 + AL((size_t)3 * 4);
static constexpr size_t OW4T = OW3B + AL((size_t)512 * 512 * 2);
static constexpr size_t OW34 = OW4T + AL((size_t)512 * 512 * 2);
static constexpr size_t OROW = OW34 + AL((size_t)512 * 512 * 2);
static constexpr size_t OCOL = OROW + AL((size_t)(V_ + 1) * 4);
static constexpr size_t OVAL = OCOL + AL((size_t)E_ * 4);
static constexpr size_t OSELF= OVAL + AL((size_t)E_ * 4);
static constexpr size_t OWS  = OSELF+ AL((size_t)V_ * 4);
static constexpr size_t OW2S = OWS  + AL((size_t)V_ * 4);

extern "C" void kernel_launch(void* const* d_in, const int* in_sizes, int n_in,
                              void* d_out, int out_size, void* d_ws, size_t ws_size,
                              hipStream_t stream){
  const float* vert  = (const float*)d_in[0];
  const float* img   = (const float*)d_in[1];
  const int*   ei    = (const int*)  d_in[2];
  const float* W1 = (const float*)d_in[3],  *b1 = (const float*)d_in[4];
  const float* W2 = (const float*)d_in[5],  *b2 = (const float*)d_in[6];
  const float* W3 = (const float*)d_in[7],  *b3 = (const float*)d_in[8];
  const float* W4 = (const float*)d_in[9],  *b4 = (const float*)d_in[10];
  const float* W5 = (const float*)d_in[11], *b5 = (const float*)d_in[12];
  const float* W6 = (const float*)d_in[13], *b6 = (const float*)d_in[14];
  const float* fcW1 = (const float*)d_in[15], *fcb1 = (const float*)d_in[16];
  const float* fcW2 = (const float*)d_in[17], *fcb2 = (const float*)d_in[18];
  const float* fcW3 = (const float*)d_in[19], *fcb3 = (const float*)d_in[20];
  float* out = (float*)d_out;

  char* ws = (char*)d_ws;
  unsigned short* XA  = (unsigned short*)(ws + OXA);
  unsigned short* XB  = (unsigned short*)(ws + OXB);
  float* VA2  = (float*)(ws + OVA2);
  float* H5   = (float*)(ws + OH5);
  float* XF   = (float*)(ws + OXF);
  float* FC1o = (float*)(ws + OFC1);
  float* FC2o = (float*)(ws + OFC2);
  float* I1   = (float*)(ws + OI1);
  float* CAT  = (float*)(ws + OCAT);
  float* P    = (float*)(ws + OP);
  float* C34  = (float*)(ws + OC34);
  float* W56  = (float*)(ws + OW56);
  float* C56  = (float*)(ws + OC56);
  unsigned short* W3B = (unsigned short*)(ws + OW3B);
  unsigned short* W4T = (unsigned short*)(ws + OW4T);
  unsigned short* W34 = (unsigned short*)(ws + OW34);
  float* PARTA = (float*)(ws + OXA);   // FC-head partials (XA free then)
  float* PARTB = (float*)(ws + OXB);   // precompute partials (XB free then)
  int*   ROW  = (int*)(ws + OROW);
  int*   COL  = (int*)(ws + OCOL);
  float* VAL  = (float*)(ws + OVAL);
  float* SELF = (float*)(ws + OSELF);
  float* WSUM = (float*)(ws + OWS);
  float* W2S  = (float*)(ws + OW2S);

  // ---- CSR + norm powers (single dispatch, no memset) ----
  k_csr<<<1, 1024, 0, stream>>>(ei, ROW, COL, VAL, SELF, WSUM, W2S);

  // ---- weight precompute ----
  k_prep<<<(2 * 512 * 512) / 256, 256, 0, stream>>>(W3, W4, W3B, W4T);
  // W34T[n4][k3] = sum_k W4T[n4,k] * W3[k3,k]
  k_gemm<64,64,2,2,2,2><<<dim3(8, 8), 256, 0, stream>>>(W4T, W3B, W34, 512, 512,
                                                        nullptr, nullptr, nullptr, 0);
  // I1 = img @ W1[3:,:]
  k_fcp<32,64><<<dim3(2, 8), 256, 0, stream>>>(img, W1 + 3 * 512, PARTB, 512, 512);
  k_fcr<<<(32 * 512 + 255) / 256, 256, 0, stream>>>(PARTB, nullptr, I1, 32 * 512, 512, 8, 0, nullptr);
  // P = [b1; W1[0:3]; I1] @ W2
  k_cat36<<<(36 * 512 + 255) / 256, 256, 0, stream>>>(b1, W1, I1, CAT);
  k_fcp<36,64><<<dim3(2, 8), 256, 0, stream>>>(CAT, W2, PARTB, 512, 512);
  k_fcr<<<(36 * 512 + 255) / 256, 256, 0, stream>>>(PARTB, nullptr, P, 36 * 512, 512, 8, 0, nullptr);
  // C34 / W56 / C56
  k_vmall<<<(512 + 1536 + 3 + 255) / 256, 256, 0, stream>>>(b3, W4, W5, W6, b5, C34, W56, C56);

  // ---- layers 1+2: VA2 = A^2 vert (fused), then x2 (vertex-major) ----
  k_agg3x2<<<B_, 1024, 0, stream>>>(vert, ROW, COL, VAL, SELF, WSUM,
                                    nullptr, nullptr, 0, VA2);
  k_x2<<<M_ / 4, 256, 0, stream>>>(VA2, P, WSUM, W2S, b2, XA);

  // ---- layers 3+4: two F=512 aggs (vertex-major) + GEMM w/ fused epilogue ----
  k_aggb<8><<<dim3(V_), 256, 0, stream>>>(XA, ROW, COL, VAL, SELF, XB);
  k_aggb<8><<<dim3(V_), 256, 0, stream>>>(XB, ROW, COL, VAL, SELF, XA);
  k_gemm<128,128,2,2,4,4><<<dim3(M_ / 128, 4), 256, 0, stream>>>(XA, W34, XB, 512, 512,
                                                                 WSUM, C34, b4, 1);

  // ---- layers 5+6: skinny GEMM to F=3, fused A^2 + epilogue ----
  k_h5<<<M_ / 4, 256, 0, stream>>>(XB, W56, H5);
  k_agg3x2<<<B_, 1024, 0, stream>>>(H5, ROW, COL, VAL, SELF, WSUM,
                                    C56, b6, 1, XF);

  // ---- FC head ----
  k_fcp<32,64><<<dim3(4, 96), 256, 0, stream>>>(XF, fcW1, PARTA, 6144, 1024);
  k_fcr<<<(B_ * 1024 + 255) / 256, 256, 0, stream>>>(PARTA, fcb1, FC1o, 32 * 1024, 1024, 96, 0, nullptr);
  k_fcp<32,64><<<dim3(4, 16), 256, 0, stream>>>(FC1o, fcW2, PARTA, 1024, 1024);
  k_fcr<<<(B_ * 1024 + 255) / 256, 256, 0, stream>>>(PARTA, fcb2, FC2o, 32 * 1024, 1024, 16, 0, nullptr);
  k_fcp<32,64><<<dim3(24, 16), 256, 0, stream>>>(FC2o, fcW3, PARTA, 1024, 6144);
  k_fcr<<<(B_ * 6144 + 255) / 256, 256, 0, stream>>>(PARTA, fcb3, out, 32 * 6144, 6144, 16, 1, vert);
}

// Round 7
// 731.405 us; speedup vs baseline: 1.0284x; 1.0195x over previous
//
#include <hip/hip_runtime.h>
#include <stdint.h>
#include <math.h>

#define B_ 32
#define V_ 2048
#define E_ 12288
#define M_ (B_*V_)

typedef __bf16 bf16x8 __attribute__((ext_vector_type(8)));
typedef float f32x4 __attribute__((ext_vector_type(4)));

__device__ __forceinline__ float bf2f(unsigned short u){
  union { unsigned int i; float f; } v; v.i = ((unsigned int)u) << 16; return v.f;
}
__device__ __forceinline__ unsigned short f2bf(float f){
  union { float f; unsigned int i; } v; v.f = f;
  unsigned int r = (v.i + 0x7fffu + ((v.i >> 16) & 1u)) >> 16;
  return (unsigned short)r;
}
__device__ __forceinline__ void gload16(const unsigned short* g, unsigned short* l){
  __builtin_amdgcn_global_load_lds(
      (const __attribute__((address_space(1))) void*)g,
      (__attribute__((address_space(3))) void*)l, 16, 0, 0);
}

// ---------------- one-shot CSR + norm powers, single block, all in LDS ----------------
__global__ __launch_bounds__(1024) void k_csr(
    const int* __restrict__ ei, int* __restrict__ rowptr_g, int* __restrict__ cols_g,
    float* __restrict__ vals_g, float* __restrict__ selfw_g,
    float* __restrict__ wsum_g, float* __restrict__ w2_g){
  __shared__ int   sdeg[V_];
  __shared__ int   srp[V_ + 1];
  __shared__ int   sfill[V_];
  __shared__ float sdinv[V_];
  __shared__ float swsum[V_];
  __shared__ float sw2[V_];
  __shared__ int   swt[16];
  const int t = threadIdx.x;
  sdeg[2*t] = 0; sdeg[2*t+1] = 0; sfill[2*t] = 0; sfill[2*t+1] = 0;
  __syncthreads();
  #pragma unroll
  for (int e = t; e < E_; e += 1024) atomicAdd(&sdeg[ei[E_ + e]], 1);
  __syncthreads();
  int c0 = sdeg[2*t], c1 = sdeg[2*t+1];
  int s2 = c0 + c1;
  int lane = t & 63, wid = t >> 6;
  int pre = s2;
  #pragma unroll
  for (int off = 1; off < 64; off <<= 1){
    int u = __shfl_up(pre, off);
    if (lane >= off) pre += u;
  }
  if (lane == 63) swt[wid] = pre;
  __syncthreads();
  if (t == 0){
    int run = 0;
    #pragma unroll
    for (int i = 0; i < 16; i++){ int x = swt[i]; swt[i] = run; run += x; }
    srp[V_] = run;
  }
  __syncthreads();
  int base = swt[wid] + (pre - s2);
  srp[2*t] = base; srp[2*t+1] = base + c0;
  #pragma unroll
  for (int v = t; v < V_; v += 1024){
    float d = (float)(sdeg[v] + 1);
    float di = rsqrtf(d);
    sdinv[v] = di;
    swsum[v] = di * di;
  }
  __syncthreads();
  #pragma unroll
  for (int e = t; e < E_; e += 1024){
    int s = ei[e], d = ei[E_ + e];
    int pos = srp[d] + atomicAdd(&sfill[d], 1);
    float val = sdinv[s] * sdinv[d];
    cols_g[pos] = s;
    vals_g[pos] = val;
    atomicAdd(&swsum[d], val);
  }
  __syncthreads();
  #pragma unroll
  for (int v = t; v < V_; v += 1024)
    sw2[v] = (sdinv[v] * sdinv[v]) * swsum[v];
  __syncthreads();
  #pragma unroll
  for (int e = t; e < E_; e += 1024){
    int s = ei[e], d = ei[E_ + e];
    atomicAdd(&sw2[d], sdinv[s] * sdinv[d] * swsum[s]);
  }
  __syncthreads();
  #pragma unroll
  for (int v = t; v < V_; v += 1024){
    rowptr_g[v] = srp[v];
    selfw_g[v]  = sdinv[v] * sdinv[v];
    wsum_g[v]   = swsum[v];
    w2_g[v]     = sw2[v];
  }
  if (t == 0) rowptr_g[V_] = srp[V_];
}

// ---------------- preA: W4T tiled transpose + W3 convert + I1 split-K partials ----------------
__global__ __launch_bounds__(256) void k_preA(
    const float* __restrict__ W3, const float* __restrict__ W4,
    const float* __restrict__ img, const float* __restrict__ W1,
    unsigned short* __restrict__ W3B, unsigned short* __restrict__ W4T,
    float* __restrict__ partB){
  __shared__ float tile[32][33];
  int blk = blockIdx.x, t = threadIdx.x;
  if (blk < 256){
    int tr0 = (blk >> 4) << 5, tc0 = (blk & 15) << 5;
    int r = t >> 5, c = t & 31;
    #pragma unroll
    for (int i = 0; i < 4; i++)
      tile[r + 8*i][c] = W4[(size_t)(tr0 + r + 8*i) * 512 + tc0 + c];
    __syncthreads();
    #pragma unroll
    for (int i = 0; i < 4; i++)
      W4T[(size_t)(tc0 + r + 8*i) * 512 + tr0 + c] = f2bf(tile[c][r + 8*i]);
  } else if (blk < 256 + 1024){
    int id = (blk - 256) * 256 + t;
    W3B[id] = f2bf(W3[id]);
  } else {
    int bx = blk - 1280;               // 16 blocks: (gx = bx&1, gy = bx>>1)
    int n = ((bx & 1) << 8) + t;
    int k0 = (bx >> 1) * 64;
    const float* W = W1 + 3 * 512;
    float acc[32] = {};
    for (int kk = 0; kk < 64; kk += 4){
      const float* wp = W + (size_t)(k0 + kk) * 512 + n;
      float w0 = wp[0], w1 = wp[512], w2 = wp[1024], w3 = wp[1536];
      #pragma unroll
      for (int r = 0; r < 32; r++){
        const float* xp = img + (size_t)r * 512 + k0 + kk;
        acc[r] += xp[0]*w0 + xp[1]*w1 + xp[2]*w2 + xp[3]*w3;
      }
    }
    float* p = partB + (size_t)(bx >> 1) * 32 * 512 + n;
    #pragma unroll
    for (int r = 0; r < 32; r++) p[(size_t)r * 512] = acc[r];
  }
}

// ---------------- preB: I1 reduce + small weight products ----------------
__global__ __launch_bounds__(256) void k_preB(
    const float* __restrict__ partB, float* __restrict__ I1,
    const float* __restrict__ b3, const float* __restrict__ W4,
    const float* __restrict__ W5, const float* __restrict__ W6,
    const float* __restrict__ b5,
    float* __restrict__ C34, float* __restrict__ W56, float* __restrict__ C56){
  int blk = blockIdx.x, t = threadIdx.x;
  if (blk < 64){
    int id = blk * 256 + t;            // 16384
    float a = 0.f;
    #pragma unroll
    for (int s = 0; s < 8; s++) a += partB[(size_t)s * 16384 + id];
    I1[id] = a;
  } else {
    int id = (blk - 64) * 256 + t;
    if (id < 512){
      float a0=0,a1=0,a2=0,a3=0;
      for (int k = 0; k < 512; k += 4){
        a0 += b3[k]   * W4[(size_t)k * 512 + id];
        a1 += b3[k+1] * W4[(size_t)(k+1) * 512 + id];
        a2 += b3[k+2] * W4[(size_t)(k+2) * 512 + id];
        a3 += b3[k+3] * W4[(size_t)(k+3) * 512 + id];
      }
      C34[id] = a0+a1+a2+a3;
    } else if (id < 512 + 1536){
      int i = id - 512; int k5 = i / 3, j = i % 3;
      float a = 0.f;
      #pragma unroll 4
      for (int u = 0; u < 64; u++) a += W5[k5 * 64 + u] * W6[u * 3 + j];
      W56[i] = a;
    } else if (id < 512 + 1536 + 3){
      int j = id - (512 + 1536);
      float a = 0.f;
      #pragma unroll 4
      for (int u = 0; u < 64; u++) a += b5[u] * W6[u * 3 + j];
      C56[j] = a;
    }
  }
}

// ---------------- preC: P split-K partials, inline CAT = [b1; W1 rows 0-2; I1] ----------------
__global__ __launch_bounds__(256) void k_preC(
    const float* __restrict__ b1, const float* __restrict__ W1,
    const float* __restrict__ I1, const float* __restrict__ W2,
    float* __restrict__ partB){
  int bx = blockIdx.x;                 // 16 blocks
  int n = ((bx & 1) << 8) + threadIdx.x;
  int k0 = (bx >> 1) * 64;
  float acc[36] = {};
  for (int kk = 0; kk < 64; kk += 4){
    int k = k0 + kk;
    const float* wp = W2 + (size_t)k * 512 + n;
    float w0 = wp[0], w1 = wp[512], w2 = wp[1024], w3 = wp[1536];
    #pragma unroll
    for (int r = 0; r < 36; r++){
      const float* q;
      if (r == 0)      q = b1 + k;
      else if (r < 4)  q = W1 + (size_t)(r - 1) * 512 + k;
      else             q = I1 + (size_t)(r - 4) * 512 + k;
      acc[r] += q[0]*w0 + q[1]*w1 + q[2]*w2 + q[3]*w3;
    }
  }
  float* p = partB + (size_t)(bx >> 1) * 36 * 512 + n;
  #pragma unroll
  for (int r = 0; r < 36; r++) p[(size_t)r * 512] = acc[r];
}

// ---------------- preD: P reduce ----------------
__global__ __launch_bounds__(256) void k_preD(
    const float* __restrict__ partB, float* __restrict__ P){
  int id = blockIdx.x * 256 + threadIdx.x;   // 18432
  float a = 0.f;
  #pragma unroll
  for (int s = 0; s < 8; s++) a += partB[(size_t)s * 18432 + id];
  P[id] = a;
}

// ---------------- VA2 = A^2 vert, per-batch LDS double hop; OUTPUT VERTEX-MAJOR ----------------
__global__ __launch_bounds__(1024) void k_va2(
    const float* __restrict__ in, const int* __restrict__ rowptr,
    const int* __restrict__ cols, const float* __restrict__ vals,
    const float* __restrict__ selfw, float* __restrict__ outv){
  __shared__ float xs[V_ * 3];
  __shared__ float ys[V_ * 3];
  int b = blockIdx.x, t = threadIdx.x;
  const float* ib = in + (size_t)b * V_ * 3;
  for (int i = t; i < V_ * 3; i += 1024) xs[i] = ib[i];
  __syncthreads();
  for (int v = t; v < V_; v += 1024){
    float sw = selfw[v];
    float a0 = sw * xs[v*3], a1 = sw * xs[v*3+1], a2 = sw * xs[v*3+2];
    int re = rowptr[v + 1];
    for (int e = rowptr[v]; e < re; e++){
      int s = cols[e]; float vv = vals[e];
      a0 += vv * xs[s*3]; a1 += vv * xs[s*3+1]; a2 += vv * xs[s*3+2];
    }
    ys[v*3] = a0; ys[v*3+1] = a1; ys[v*3+2] = a2;
  }
  __syncthreads();
  for (int v = t; v < V_; v += 1024){
    float sw = selfw[v];
    float a0 = sw * ys[v*3], a1 = sw * ys[v*3+1], a2 = sw * ys[v*3+2];
    int re = rowptr[v + 1];
    for (int e = rowptr[v]; e < re; e++){
      int s = cols[e]; float vv = vals[e];
      a0 += vv * ys[s*3]; a1 += vv * ys[s*3+1]; a2 += vv * ys[s*3+2];
    }
    float* o = outv + ((size_t)v * 32 + b) * 3;    // vertex-major
    o[0] = a0; o[1] = a1; o[2] = a2;
  }
}

// ---------------- k_y1: fused x2-on-the-fly + A-hop. Y1[dst][b][f] (vertex-major bf16) ----------------
// x2[s][b][f] = relu(va2v[s,b].wv[f] + w2[s]*I[b][f] + wsum[s]*c12[f] + b2[f])
__global__ __launch_bounds__(256) void k_y1(
    const float* __restrict__ va2v, const float* __restrict__ P,
    const float* __restrict__ wsum, const float* __restrict__ w2s,
    const float* __restrict__ b2,
    const int* __restrict__ rowptr, const int* __restrict__ cols,
    const float* __restrict__ vals, const float* __restrict__ selfw,
    unsigned short* __restrict__ Y){
  int dst = blockIdx.x;
  int batch = (blockIdx.y << 2) + (threadIdx.x >> 6);
  int f8 = (threadIdx.x & 63) * 8;
  float wv0[8], wv1[8], wv2[8], cc[8], bb[8], ii[8];
  #pragma unroll
  for (int j = 0; j < 8; j++){
    int fc = f8 + j;
    wv0[j] = P[512 + fc]; wv1[j] = P[1024 + fc]; wv2[j] = P[1536 + fc];
    cc[j]  = P[fc];       bb[j]  = b2[fc];
    ii[j]  = P[2048 + (size_t)batch * 512 + fc];
  }
  float acc[8] = {};
  int rs = rowptr[dst], re = rowptr[dst + 1];
  // self + edges
  for (int e = rs - 1; e < re; e++){
    int s; float w;
    if (e < rs){ s = dst; w = selfw[dst]; }
    else       { s = cols[e]; w = vals[e]; }
    const float* va = va2v + ((size_t)s * 32 + batch) * 3;
    float x0 = va[0], x1 = va[1], x2 = va[2];
    float w2v = w2s[s], wsv = wsum[s];
    #pragma unroll
    for (int j = 0; j < 8; j++){
      float tv = x0*wv0[j] + x1*wv1[j] + x2*wv2[j] + w2v*ii[j] + wsv*cc[j] + bb[j];
      tv = fmaxf(tv, 0.f);
      acc[j] += w * tv;
    }
  }
  unsigned int o[4];
  #pragma unroll
  for (int i = 0; i < 4; i++)
    o[i] = (unsigned int)f2bf(acc[2*i]) | ((unsigned int)f2bf(acc[2*i+1]) << 16);
  *(uint4*)&Y[((size_t)dst * 32 + batch) * 512 + f8] = *(uint4*)o;
}

// ---------------- F=512 bf16 aggregation, vertex-major, wave-per-batch, edge-unroll x2 ----------------
__global__ __launch_bounds__(256) void k_aggb(
    const unsigned short* __restrict__ Hg, const int* __restrict__ rowptr,
    const int* __restrict__ cols, const float* __restrict__ vals,
    const float* __restrict__ selfw, unsigned short* __restrict__ Xo){
  int dst = blockIdx.x;
  int batch = (blockIdx.y << 2) + (threadIdx.x >> 6);
  int f8 = (threadIdx.x & 63) * 8;
  int rs = rowptr[dst], re = rowptr[dst + 1];
  float sw = selfw[dst];
  float a[8];
  {
    uint4 q = *(const uint4*)&Hg[((size_t)dst * 32 + batch) * 512 + f8];
    const unsigned int* w = (const unsigned int*)&q;
    #pragma unroll
    for (int i = 0; i < 4; i++){
      a[2*i]   = sw * bf2f(w[i] & 0xffff);
      a[2*i+1] = sw * bf2f(w[i] >> 16);
    }
  }
  int e = rs;
  for (; e + 1 < re; e += 2){
    int s0 = cols[e], s1 = cols[e+1];
    float v0 = vals[e], v1 = vals[e+1];
    uint4 q0 = *(const uint4*)&Hg[((size_t)s0 * 32 + batch) * 512 + f8];
    uint4 q1 = *(const uint4*)&Hg[((size_t)s1 * 32 + batch) * 512 + f8];
    const unsigned int* w0 = (const unsigned int*)&q0;
    const unsigned int* w1 = (const unsigned int*)&q1;
    #pragma unroll
    for (int i = 0; i < 4; i++){
      a[2*i]   += v0 * bf2f(w0[i] & 0xffff) + v1 * bf2f(w1[i] & 0xffff);
      a[2*i+1] += v0 * bf2f(w0[i] >> 16)    + v1 * bf2f(w1[i] >> 16);
    }
  }
  if (e < re){
    int s = cols[e]; float v = vals[e];
    uint4 q = *(const uint4*)&Hg[((size_t)s * 32 + batch) * 512 + f8];
    const unsigned int* w = (const unsigned int*)&q;
    #pragma unroll
    for (int i = 0; i < 4; i++){
      a[2*i]   += v * bf2f(w[i] & 0xffff);
      a[2*i+1] += v * bf2f(w[i] >> 16);
    }
  }
  unsigned int o[4];
  #pragma unroll
  for (int i = 0; i < 4; i++)
    o[i] = (unsigned int)f2bf(a[2*i]) | ((unsigned int)f2bf(a[2*i+1]) << 16);
  *(uint4*)&Xo[((size_t)dst * 32 + batch) * 512 + f8] = *(uint4*)o;
}

// ---------------- bf16 MFMA GEMM: A AND B double-buffered via global_load_lds, 1 barrier/iter ----------------
template<int BM, int BN, int WM, int WN, int TM, int TN>
__global__ __launch_bounds__(WM*WN*64) void k_gemm(
    const unsigned short* __restrict__ Xg, const unsigned short* __restrict__ Wt,
    unsigned short* __restrict__ Hg, int K, int N,
    const float* __restrict__ wsumv, const float* __restrict__ cvec,
    const float* __restrict__ bias, int relu){
  constexpr int BK = 32;
  constexpr int NW = WM * WN;
  constexpr int RA = BM / NW;
  constexpr int RB = BN / NW;
  __shared__ __align__(16) unsigned short As[2][BM * BK];
  __shared__ __align__(16) unsigned short Bs[2][BN * BK];
  const int tid = threadIdx.x;
  const int row0 = blockIdx.x * BM, col0 = blockIdx.y * BN;
  const int wave = tid >> 6, lane = tid & 63;
  const int wr = wave / WN, wc = wave % WN;
  const int lrow = lane & 15, lq = lane >> 4;
  const int lrw = lane >> 2, lcol = (lane & 3) * 8;
  const int arow = wave * RA, brow = wave * RB;
  f32x4 acc[TM][TN] = {};
  #pragma unroll
  for (int t = 0; t < RA / 16; t++)
    gload16(&Xg[(size_t)(row0 + arow + t * 16 + lrw) * K + lcol],
            &As[0][(arow + t * 16) * BK]);
  #pragma unroll
  for (int t = 0; t < RB / 16; t++)
    gload16(&Wt[(size_t)(col0 + brow + t * 16 + lrw) * K + lcol],
            &Bs[0][(brow + t * 16) * BK]);
  int cur = 0;
  for (int k0 = 0; k0 < K; k0 += BK){
    __syncthreads();
    if (k0 + BK < K){
      #pragma unroll
      for (int t = 0; t < RA / 16; t++)
        gload16(&Xg[(size_t)(row0 + arow + t * 16 + lrw) * K + k0 + BK + lcol],
                &As[cur ^ 1][(arow + t * 16) * BK]);
      #pragma unroll
      for (int t = 0; t < RB / 16; t++)
        gload16(&Wt[(size_t)(col0 + brow + t * 16 + lrw) * K + k0 + BK + lcol],
                &Bs[cur ^ 1][(brow + t * 16) * BK]);
    }
    bf16x8 af[TM], bfr[TN];
    #pragma unroll
    for (int tm = 0; tm < TM; tm++)
      af[tm] = *(const bf16x8*)&As[cur][(wr * TM * 16 + tm * 16 + lrow) * BK + lq * 8];
    #pragma unroll
    for (int tn = 0; tn < TN; tn++)
      bfr[tn] = *(const bf16x8*)&Bs[cur][(wc * TN * 16 + tn * 16 + lrow) * BK + lq * 8];
    #pragma unroll
    for (int tm = 0; tm < TM; tm++)
      #pragma unroll
      for (int tn = 0; tn < TN; tn++)
        acc[tm][tn] = __builtin_amdgcn_mfma_f32_16x16x32_bf16(af[tm], bfr[tn], acc[tm][tn], 0, 0, 0);
    cur ^= 1;
  }
  #pragma unroll
  for (int tm = 0; tm < TM; tm++){
    #pragma unroll
    for (int tn = 0; tn < TN; tn++){
      int col = col0 + wc * TN * 16 + tn * 16 + lrow;
      float cv = 0.f, bv = 0.f;
      if (cvec){ cv = cvec[col]; bv = bias[col]; }
      #pragma unroll
      for (int r = 0; r < 4; r++){
        int row = row0 + wr * TM * 16 + tm * 16 + lq * 4 + r;
        float x = acc[tm][tn][r];
        if (cvec) x += wsumv[row >> 5] * cv + bv;   // vertex-major rows
        if (relu) x = fmaxf(x, 0.f);
        Hg[(size_t)row * N + col] = f2bf(x);
      }
    }
  }
}

// ---------------- k_xf: fused (x4@W56) + A^2 + epilogue, per-batch block ----------------
__global__ __launch_bounds__(1024) void k_xf(
    const unsigned short* __restrict__ x4, const float* __restrict__ W56,
    const int* __restrict__ rowptr, const int* __restrict__ cols,
    const float* __restrict__ vals, const float* __restrict__ selfw,
    const float* __restrict__ wsum, const float* __restrict__ C56,
    const float* __restrict__ b6, float* __restrict__ XF){
  __shared__ float xs[V_ * 3];
  __shared__ float ys[V_ * 3];
  __shared__ float w56s[512 * 3];
  int b = blockIdx.x, t = threadIdx.x;
  for (int i = t; i < 1536; i += 1024) w56s[i] = W56[i];
  __syncthreads();
  // phase 0: wave per row dot with W56
  int wid = t >> 6, lane = t & 63;
  for (int v = wid; v < V_; v += 16){
    uint4 q = *(const uint4*)&x4[(((size_t)v << 5) + b) * 512 + lane * 8];
    const unsigned int* w = (const unsigned int*)&q;
    float a0 = 0.f, a1 = 0.f, a2 = 0.f;
    #pragma unroll
    for (int i = 0; i < 8; i++){
      float x = bf2f((i & 1) ? (unsigned short)(w[i >> 1] >> 16)
                             : (unsigned short)(w[i >> 1] & 0xffff));
      int k = lane * 8 + i;
      a0 += x * w56s[k * 3]; a1 += x * w56s[k * 3 + 1]; a2 += x * w56s[k * 3 + 2];
    }
    #pragma unroll
    for (int off = 32; off; off >>= 1){
      a0 += __shfl_down(a0, off);
      a1 += __shfl_down(a1, off);
      a2 += __shfl_down(a2, off);
    }
    if (lane == 0){ xs[v*3] = a0; xs[v*3+1] = a1; xs[v*3+2] = a2; }
  }
  __syncthreads();
  // hop 1
  for (int v = t; v < V_; v += 1024){
    float sw = selfw[v];
    float a0 = sw * xs[v*3], a1 = sw * xs[v*3+1], a2 = sw * xs[v*3+2];
    int re = rowptr[v + 1];
    for (int e = rowptr[v]; e < re; e++){
      int s = cols[e]; float vv = vals[e];
      a0 += vv * xs[s*3]; a1 += vv * xs[s*3+1]; a2 += vv * xs[s*3+2];
    }
    ys[v*3] = a0; ys[v*3+1] = a1; ys[v*3+2] = a2;
  }
  __syncthreads();
  // hop 2 + epilogue -> batch-major XF
  float* ob = XF + (size_t)b * V_ * 3;
  for (int v = t; v < V_; v += 1024){
    float sw = selfw[v];
    float a0 = sw * ys[v*3], a1 = sw * ys[v*3+1], a2 = sw * ys[v*3+2];
    int re = rowptr[v + 1];
    for (int e = rowptr[v]; e < re; e++){
      int s = cols[e]; float vv = vals[e];
      a0 += vv * ys[s*3]; a1 += vv * ys[s*3+1]; a2 += vv * ys[s*3+2];
    }
    float w = wsum[v];
    a0 = fmaxf(a0 + w * C56[0] + b6[0], 0.f);
    a1 = fmaxf(a1 + w * C56[1] + b6[1], 0.f);
    a2 = fmaxf(a2 + w * C56[2] + b6[2], 0.f);
    ob[v*3] = a0; ob[v*3+1] = a1; ob[v*3+2] = a2;
  }
}

// ---------------- FC split-K stage A ----------------
template<int R, int KC>
__global__ __launch_bounds__(256) void k_fcp(
    const float* __restrict__ in, const float* __restrict__ W,
    float* __restrict__ partial, int K, int N){
  const int n = blockIdx.x * 256 + threadIdx.x;
  const int k0 = blockIdx.y * KC;
  float acc[R] = {};
  for (int kk = 0; kk < KC; kk += 4){
    const float* wp = W + (size_t)(k0 + kk) * N + n;
    float w0 = wp[0];
    float w1 = wp[(size_t)N];
    float w2 = wp[(size_t)2 * N];
    float w3 = wp[(size_t)3 * N];
    #pragma unroll
    for (int r = 0; r < R; r++){
      const float* xp = in + (size_t)r * K + k0 + kk;
      acc[r] += xp[0]*w0 + xp[1]*w1 + xp[2]*w2 + xp[3]*w3;
    }
  }
  float* p = partial + (size_t)blockIdx.y * R * N + n;
  #pragma unroll
  for (int r = 0; r < R; r++) p[(size_t)r * N] = acc[r];
}

// ---------------- FC split-K stage B ----------------
__global__ __launch_bounds__(256) void k_fcr(
    const float* __restrict__ partial, const float* __restrict__ bias,
    float* __restrict__ out, int total, int N, int KS, int mode,
    const float* __restrict__ vert){
  int id = blockIdx.x * 256 + threadIdx.x;
  if (id >= total) return;
  int n = id % N;
  float a0 = 0.f, a1 = 0.f, a2 = 0.f, a3 = 0.f;
  int s = 0;
  for (; s + 4 <= KS; s += 4){
    a0 += partial[(size_t)s * total + id];
    a1 += partial[(size_t)(s + 1) * total + id];
    a2 += partial[(size_t)(s + 2) * total + id];
    a3 += partial[(size_t)(s + 3) * total + id];
  }
  for (; s < KS; s++) a0 += partial[(size_t)s * total + id];
  float acc = a0 + a1 + a2 + a3;
  if (bias) acc += bias[n];
  if (mode) acc = vert[id] + 0.1f * tanhf(acc);
  out[id] = acc;
}

// ---------------- workspace layout ----------------
static constexpr size_t AL(size_t x){ return (x + 255) & ~(size_t)255; }
static constexpr size_t S512 = (size_t)M_ * 512 * 2;
static constexpr size_t S3   = (size_t)M_ * 3 * 4;
static constexpr size_t OXA  = 0;                       // A^2 x2 / FC partials
static constexpr size_t OXB  = OXA  + AL(S512);         // Y1 & x4 / precompute partials
static constexpr size_t OVA2 = OXB  + AL(S512);
static constexpr size_t OXF  = OVA2 + AL(S3);
static constexpr size_t OFC1 = OXF  + AL(S3);
static constexpr size_t OFC2 = OFC1 + AL((size_t)B_ * 1024 * 4);
static constexpr size_t OI1  = OFC2 + AL((size_t)B_ * 1024 * 4);
static constexpr size_t OP   = OI1  + AL((size_t)32 * 512 * 4);
static constexpr size_t OC34 = OP   + AL((size_t)36 * 512 * 4);
static constexpr size_t OW56 = OC34 + AL((size_t)512 * 4);
static constexpr size_t OC56 = OW56 + AL((size_t)512 * 3 * 4);
static constexpr size_t OW3B = OC56 + AL((size_t)3 * 4);
static constexpr size_t OW4T = OW3B + AL((size_t)512 * 512 * 2);
static constexpr size_t OW34 = OW4T + AL((size_t)512 * 512 * 2);
static constexpr size_t OROW = OW34 + AL((size_t)512 * 512 * 2);
static constexpr size_t OCOL = OROW + AL((size_t)(V_ + 1) * 4);
static constexpr size_t OVAL = OCOL + AL((size_t)E_ * 4);
static constexpr size_t OSELF= OVAL + AL((size_t)E_ * 4);
static constexpr size_t OWS  = OSELF+ AL((size_t)V_ * 4);
static constexpr size_t OW2S = OWS  + AL((size_t)V_ * 4);

extern "C" void kernel_launch(void* const* d_in, const int* in_sizes, int n_in,
                              void* d_out, int out_size, void* d_ws, size_t ws_size,
                              hipStream_t stream){
  const float* vert  = (const float*)d_in[0];
  const float* img   = (const float*)d_in[1];
  const int*   ei    = (const int*)  d_in[2];
  const float* W1 = (const float*)d_in[3],  *b1 = (const float*)d_in[4];
  const float* W2 = (const float*)d_in[5],  *b2 = (const float*)d_in[6];
  const float* W3 = (const float*)d_in[7],  *b3 = (const float*)d_in[8];
  const float* W4 = (const float*)d_in[9],  *b4 = (const float*)d_in[10];
  const float* W5 = (const float*)d_in[11], *b5 = (const float*)d_in[12];
  const float* W6 = (const float*)d_in[13], *b6 = (const float*)d_in[14];
  const float* fcW1 = (const float*)d_in[15], *fcb1 = (const float*)d_in[16];
  const float* fcW2 = (const float*)d_in[17], *fcb2 = (const float*)d_in[18];
  const float* fcW3 = (const float*)d_in[19], *fcb3 = (const float*)d_in[20];
  float* out = (float*)d_out;

  char* ws = (char*)d_ws;
  unsigned short* XA  = (unsigned short*)(ws + OXA);
  unsigned short* XB  = (unsigned short*)(ws + OXB);
  float* VA2v = (float*)(ws + OVA2);
  float* XF   = (float*)(ws + OXF);
  float* FC1o = (float*)(ws + OFC1);
  float* FC2o = (float*)(ws + OFC2);
  float* I1   = (float*)(ws + OI1);
  float* P    = (float*)(ws + OP);
  float* C34  = (float*)(ws + OC34);
  float* W56  = (float*)(ws + OW56);
  float* C56  = (float*)(ws + OC56);
  unsigned short* W3B = (unsigned short*)(ws + OW3B);
  unsigned short* W4T = (unsigned short*)(ws + OW4T);
  unsigned short* W34 = (unsigned short*)(ws + OW34);
  float* PARTA = (float*)(ws + OXA);
  float* PARTB = (float*)(ws + OXB);
  int*   ROW  = (int*)(ws + OROW);
  int*   COL  = (int*)(ws + OCOL);
  float* VAL  = (float*)(ws + OVAL);
  float* SELF = (float*)(ws + OSELF);
  float* WSUM = (float*)(ws + OWS);
  float* W2S  = (float*)(ws + OW2S);

  // ---- CSR + norm powers ----
  k_csr<<<1, 1024, 0, stream>>>(ei, ROW, COL, VAL, SELF, WSUM, W2S);

  // ---- precompute (5 dispatches) ----
  k_preA<<<256 + 1024 + 16, 256, 0, stream>>>(W3, W4, img, W1, W3B, W4T, PARTB);
  k_preB<<<64 + 9, 256, 0, stream>>>(PARTB, I1, b3, W4, W5, W6, b5, C34, W56, C56);
  k_preC<<<16, 256, 0, stream>>>(b1, W1, I1, W2, PARTB);
  k_preD<<<72, 256, 0, stream>>>(PARTB, P);
  // W34T[n4][k3] = sum_k W4T[n4,k] * W3[k3,k]
  k_gemm<64,64,2,2,2,2><<<dim3(8, 8), 256, 0, stream>>>(W4T, W3B, W34, 512, 512,
                                                        nullptr, nullptr, nullptr, 0);

  // ---- layers 1-3a: VA2 (vertex-major), then fused x2+A-hop ----
  k_va2<<<B_, 1024, 0, stream>>>(vert, ROW, COL, VAL, SELF, VA2v);
  k_y1<<<dim3(V_, 8), 256, 0, stream>>>(VA2v, P, WSUM, W2S, b2, ROW, COL, VAL, SELF, XB);

  // ---- second A-hop + GEMM w/ fused epilogue ----
  k_aggb<<<dim3(V_, 8), 256, 0, stream>>>(XB, ROW, COL, VAL, SELF, XA);
  k_gemm<128,128,2,2,4,4><<<dim3(M_ / 128, 4), 256, 0, stream>>>(XA, W34, XB, 512, 512,
                                                                 WSUM, C34, b4, 1);

  // ---- layers 5+6 fused: (x4@W56) + A^2 + epilogue ----
  k_xf<<<B_, 1024, 0, stream>>>(XB, W56, ROW, COL, VAL, SELF, WSUM, C56, b6, XF);

  // ---- FC head ----
  k_fcp<32,64><<<dim3(4, 96), 256, 0, stream>>>(XF, fcW1, PARTA, 6144, 1024);
  k_fcr<<<(B_ * 1024 + 255) / 256, 256, 0, stream>>>(PARTA, fcb1, FC1o, 32 * 1024, 1024, 96, 0, nullptr);
  k_fcp<32,64><<<dim3(4, 16), 256, 0, stream>>>(FC1o, fcW2, PARTA, 1024, 1024);
  k_fcr<<<(B_ * 1024 + 255) / 256, 256, 0, stream>>>(PARTA, fcb2, FC2o, 32 * 1024, 1024, 16, 0, nullptr);
  k_fcp<32,64><<<dim3(24, 16), 256, 0, stream>>>(FC2o, fcW3, PARTA, 1024, 6144);
  k_fcr<<<(B_ * 6144 + 255) / 256, 256, 0, stream>>>(PARTA, fcb3, out, 32 * 6144, 6144, 16, 1, vert);
}

// Round 8
// 629.665 us; speedup vs baseline: 1.1945x; 1.1616x over previous
//
#include <hip/hip_runtime.h>
#include <stdint.h>
#include <math.h>

#define B_ 32
#define V_ 2048
#define E_ 12288
#define M_ (B_*V_)

typedef __bf16 bf16x8 __attribute__((ext_vector_type(8)));
typedef float f32x4 __attribute__((ext_vector_type(4)));

__device__ __forceinline__ float bf2f(unsigned short u){
  union { unsigned int i; float f; } v; v.i = ((unsigned int)u) << 16; return v.f;
}
__device__ __forceinline__ unsigned short f2bf(float f){
  union { float f; unsigned int i; } v; v.f = f;
  unsigned int r = (v.i + 0x7fffu + ((v.i >> 16) & 1u)) >> 16;
  return (unsigned short)r;
}
__device__ __forceinline__ void gload16(const unsigned short* g, unsigned short* l){
  __builtin_amdgcn_global_load_lds(
      (const __attribute__((address_space(1))) void*)g,
      (__attribute__((address_space(3))) void*)l, 16, 0, 0);
}

// ---------------- one-shot CSR + norm powers, single block, all in LDS ----------------
__global__ __launch_bounds__(1024) void k_csr(
    const int* __restrict__ ei, int* __restrict__ rowptr_g, int* __restrict__ cols_g,
    float* __restrict__ vals_g, float* __restrict__ selfw_g,
    float* __restrict__ wsum_g, float* __restrict__ w2_g){
  __shared__ int   sdeg[V_];
  __shared__ int   srp[V_ + 1];
  __shared__ int   sfill[V_];
  __shared__ float sdinv[V_];
  __shared__ float swsum[V_];
  __shared__ float sw2[V_];
  __shared__ int   swt[16];
  const int t = threadIdx.x;
  sdeg[2*t] = 0; sdeg[2*t+1] = 0; sfill[2*t] = 0; sfill[2*t+1] = 0;
  __syncthreads();
  #pragma unroll
  for (int e = t; e < E_; e += 1024) atomicAdd(&sdeg[ei[E_ + e]], 1);
  __syncthreads();
  int c0 = sdeg[2*t], c1 = sdeg[2*t+1];
  int s2 = c0 + c1;
  int lane = t & 63, wid = t >> 6;
  int pre = s2;
  #pragma unroll
  for (int off = 1; off < 64; off <<= 1){
    int u = __shfl_up(pre, off);
    if (lane >= off) pre += u;
  }
  if (lane == 63) swt[wid] = pre;
  __syncthreads();
  if (t == 0){
    int run = 0;
    #pragma unroll
    for (int i = 0; i < 16; i++){ int x = swt[i]; swt[i] = run; run += x; }
    srp[V_] = run;
  }
  __syncthreads();
  int base = swt[wid] + (pre - s2);
  srp[2*t] = base; srp[2*t+1] = base + c0;
  #pragma unroll
  for (int v = t; v < V_; v += 1024){
    float d = (float)(sdeg[v] + 1);
    float di = rsqrtf(d);
    sdinv[v] = di;
    swsum[v] = di * di;
  }
  __syncthreads();
  #pragma unroll
  for (int e = t; e < E_; e += 1024){
    int s = ei[e], d = ei[E_ + e];
    int pos = srp[d] + atomicAdd(&sfill[d], 1);
    float val = sdinv[s] * sdinv[d];
    cols_g[pos] = s;
    vals_g[pos] = val;
    atomicAdd(&swsum[d], val);
  }
  __syncthreads();
  #pragma unroll
  for (int v = t; v < V_; v += 1024)
    sw2[v] = (sdinv[v] * sdinv[v]) * swsum[v];
  __syncthreads();
  #pragma unroll
  for (int e = t; e < E_; e += 1024){
    int s = ei[e], d = ei[E_ + e];
    atomicAdd(&sw2[d], sdinv[s] * sdinv[d] * swsum[s]);
  }
  __syncthreads();
  #pragma unroll
  for (int v = t; v < V_; v += 1024){
    rowptr_g[v] = srp[v];
    selfw_g[v]  = sdinv[v] * sdinv[v];
    wsum_g[v]   = swsum[v];
    w2_g[v]     = sw2[v];
  }
  if (t == 0) rowptr_g[V_] = srp[V_];
}

// ---------------- preA: W4T tiled transpose + W3 convert + I1 split-K partials ----------------
__global__ __launch_bounds__(256) void k_preA(
    const float* __restrict__ W3, const float* __restrict__ W4,
    const float* __restrict__ img, const float* __restrict__ W1,
    unsigned short* __restrict__ W3B, unsigned short* __restrict__ W4T,
    float* __restrict__ partB){
  __shared__ float tile[32][33];
  int blk = blockIdx.x, t = threadIdx.x;
  if (blk < 256){
    int tr0 = (blk >> 4) << 5, tc0 = (blk & 15) << 5;
    int r = t >> 5, c = t & 31;
    #pragma unroll
    for (int i = 0; i < 4; i++)
      tile[r + 8*i][c] = W4[(size_t)(tr0 + r + 8*i) * 512 + tc0 + c];
    __syncthreads();
    #pragma unroll
    for (int i = 0; i < 4; i++)
      W4T[(size_t)(tc0 + r + 8*i) * 512 + tr0 + c] = f2bf(tile[c][r + 8*i]);
  } else if (blk < 256 + 1024){
    int id = (blk - 256) * 256 + t;
    W3B[id] = f2bf(W3[id]);
  } else {
    int bx = blk - 1280;
    int n = ((bx & 1) << 8) + t;
    int k0 = (bx >> 1) * 64;
    const float* W = W1 + 3 * 512;
    float acc[32] = {};
    for (int kk = 0; kk < 64; kk += 4){
      const float* wp = W + (size_t)(k0 + kk) * 512 + n;
      float w0 = wp[0], w1 = wp[512], w2 = wp[1024], w3 = wp[1536];
      #pragma unroll
      for (int r = 0; r < 32; r++){
        const float* xp = img + (size_t)r * 512 + k0 + kk;
        acc[r] += xp[0]*w0 + xp[1]*w1 + xp[2]*w2 + xp[3]*w3;
      }
    }
    float* p = partB + (size_t)(bx >> 1) * 32 * 512 + n;
    #pragma unroll
    for (int r = 0; r < 32; r++) p[(size_t)r * 512] = acc[r];
  }
}

// ---------------- preB: I1 reduce + small weight products ----------------
__global__ __launch_bounds__(256) void k_preB(
    const float* __restrict__ partB, float* __restrict__ I1,
    const float* __restrict__ b3, const float* __restrict__ W4,
    const float* __restrict__ W5, const float* __restrict__ W6,
    const float* __restrict__ b5,
    float* __restrict__ C34, float* __restrict__ W56, float* __restrict__ C56){
  int blk = blockIdx.x, t = threadIdx.x;
  if (blk < 64){
    int id = blk * 256 + t;
    float a = 0.f;
    #pragma unroll
    for (int s = 0; s < 8; s++) a += partB[(size_t)s * 16384 + id];
    I1[id] = a;
  } else {
    int id = (blk - 64) * 256 + t;
    if (id < 512){
      float a0=0,a1=0,a2=0,a3=0;
      for (int k = 0; k < 512; k += 4){
        a0 += b3[k]   * W4[(size_t)k * 512 + id];
        a1 += b3[k+1] * W4[(size_t)(k+1) * 512 + id];
        a2 += b3[k+2] * W4[(size_t)(k+2) * 512 + id];
        a3 += b3[k+3] * W4[(size_t)(k+3) * 512 + id];
      }
      C34[id] = a0+a1+a2+a3;
    } else if (id < 512 + 1536){
      int i = id - 512; int k5 = i / 3, j = i % 3;
      float a = 0.f;
      #pragma unroll 4
      for (int u = 0; u < 64; u++) a += W5[k5 * 64 + u] * W6[u * 3 + j];
      W56[i] = a;
    } else if (id < 512 + 1536 + 3){
      int j = id - (512 + 1536);
      float a = 0.f;
      #pragma unroll 4
      for (int u = 0; u < 64; u++) a += b5[u] * W6[u * 3 + j];
      C56[j] = a;
    }
  }
}

// ---------------- preC: P split-K partials, inline CAT = [b1; W1 rows 0-2; I1] ----------------
__global__ __launch_bounds__(256) void k_preC(
    const float* __restrict__ b1, const float* __restrict__ W1,
    const float* __restrict__ I1, const float* __restrict__ W2,
    float* __restrict__ partB){
  int bx = blockIdx.x;
  int n = ((bx & 1) << 8) + threadIdx.x;
  int k0 = (bx >> 1) * 64;
  float acc[36] = {};
  for (int kk = 0; kk < 64; kk += 4){
    int k = k0 + kk;
    const float* wp = W2 + (size_t)k * 512 + n;
    float w0 = wp[0], w1 = wp[512], w2 = wp[1024], w3 = wp[1536];
    #pragma unroll
    for (int r = 0; r < 36; r++){
      const float* q;
      if (r == 0)      q = b1 + k;
      else if (r < 4)  q = W1 + (size_t)(r - 1) * 512 + k;
      else             q = I1 + (size_t)(r - 4) * 512 + k;
      acc[r] += q[0]*w0 + q[1]*w1 + q[2]*w2 + q[3]*w3;
    }
  }
  float* p = partB + (size_t)(bx >> 1) * 36 * 512 + n;
  #pragma unroll
  for (int r = 0; r < 36; r++) p[(size_t)r * 512] = acc[r];
}

// ---------------- preD: P reduce ----------------
__global__ __launch_bounds__(256) void k_preD(
    const float* __restrict__ partB, float* __restrict__ P){
  int id = blockIdx.x * 256 + threadIdx.x;
  float a = 0.f;
  #pragma unroll
  for (int s = 0; s < 8; s++) a += partB[(size_t)s * 18432 + id];
  P[id] = a;
}

// ---------------- VA2 = A^2 vert, per-batch LDS double hop; OUTPUT VERTEX-MAJOR ----------------
__global__ __launch_bounds__(1024) void k_va2(
    const float* __restrict__ in, const int* __restrict__ rowptr,
    const int* __restrict__ cols, const float* __restrict__ vals,
    const float* __restrict__ selfw, float* __restrict__ outv){
  __shared__ float xs[V_ * 3];
  __shared__ float ys[V_ * 3];
  int b = blockIdx.x, t = threadIdx.x;
  const float* ib = in + (size_t)b * V_ * 3;
  for (int i = t; i < V_ * 3; i += 1024) xs[i] = ib[i];
  __syncthreads();
  for (int v = t; v < V_; v += 1024){
    float sw = selfw[v];
    float a0 = sw * xs[v*3], a1 = sw * xs[v*3+1], a2 = sw * xs[v*3+2];
    int re = rowptr[v + 1];
    for (int e = rowptr[v]; e < re; e++){
      int s = cols[e]; float vv = vals[e];
      a0 += vv * xs[s*3]; a1 += vv * xs[s*3+1]; a2 += vv * xs[s*3+2];
    }
    ys[v*3] = a0; ys[v*3+1] = a1; ys[v*3+2] = a2;
  }
  __syncthreads();
  for (int v = t; v < V_; v += 1024){
    float sw = selfw[v];
    float a0 = sw * ys[v*3], a1 = sw * ys[v*3+1], a2 = sw * ys[v*3+2];
    int re = rowptr[v + 1];
    for (int e = rowptr[v]; e < re; e++){
      int s = cols[e]; float vv = vals[e];
      a0 += vv * ys[s*3]; a1 += vv * ys[s*3+1]; a2 += vv * ys[s*3+2];
    }
    float* o = outv + ((size_t)v * 32 + b) * 3;
    o[0] = a0; o[1] = a1; o[2] = a2;
  }
}

// ---------------- k_y1: fused x2-on-the-fly + A-hop. Y1[dst][b][f] (vertex-major bf16) ----------------
__global__ __launch_bounds__(256) void k_y1(
    const float* __restrict__ va2v, const float* __restrict__ P,
    const float* __restrict__ wsum, const float* __restrict__ w2s,
    const float* __restrict__ b2,
    const int* __restrict__ rowptr, const int* __restrict__ cols,
    const float* __restrict__ vals, const float* __restrict__ selfw,
    unsigned short* __restrict__ Y){
  int dst = blockIdx.x;
  int batch = (blockIdx.y << 2) + (threadIdx.x >> 6);
  int f8 = (threadIdx.x & 63) * 8;
  float wv0[8], wv1[8], wv2[8], cc[8], bb[8], ii[8];
  #pragma unroll
  for (int j = 0; j < 8; j++){
    int fc = f8 + j;
    wv0[j] = P[512 + fc]; wv1[j] = P[1024 + fc]; wv2[j] = P[1536 + fc];
    cc[j]  = P[fc];       bb[j]  = b2[fc];
    ii[j]  = P[2048 + (size_t)batch * 512 + fc];
  }
  float acc[8] = {};
  int rs = rowptr[dst], re = rowptr[dst + 1];
  for (int e = rs - 1; e < re; e++){
    int s; float w;
    if (e < rs){ s = dst; w = selfw[dst]; }
    else       { s = cols[e]; w = vals[e]; }
    const float* va = va2v + ((size_t)s * 32 + batch) * 3;
    float x0 = va[0], x1 = va[1], x2 = va[2];
    float w2v = w2s[s], wsv = wsum[s];
    #pragma unroll
    for (int j = 0; j < 8; j++){
      float tv = x0*wv0[j] + x1*wv1[j] + x2*wv2[j] + w2v*ii[j] + wsv*cc[j] + bb[j];
      tv = fmaxf(tv, 0.f);
      acc[j] += w * tv;
    }
  }
  unsigned int o[4];
  #pragma unroll
  for (int i = 0; i < 4; i++)
    o[i] = (unsigned int)f2bf(acc[2*i]) | ((unsigned int)f2bf(acc[2*i+1]) << 16);
  *(uint4*)&Y[((size_t)dst * 32 + batch) * 512 + f8] = *(uint4*)o;
}

// ---------------- F=512 bf16 aggregation, vertex-major, wave-per-batch, edge-unroll x2 ----------------
__global__ __launch_bounds__(256) void k_aggb(
    const unsigned short* __restrict__ Hg, const int* __restrict__ rowptr,
    const int* __restrict__ cols, const float* __restrict__ vals,
    const float* __restrict__ selfw, unsigned short* __restrict__ Xo){
  int dst = blockIdx.x;
  int batch = (blockIdx.y << 2) + (threadIdx.x >> 6);
  int f8 = (threadIdx.x & 63) * 8;
  int rs = rowptr[dst], re = rowptr[dst + 1];
  float sw = selfw[dst];
  float a[8];
  {
    uint4 q = *(const uint4*)&Hg[((size_t)dst * 32 + batch) * 512 + f8];
    const unsigned int* w = (const unsigned int*)&q;
    #pragma unroll
    for (int i = 0; i < 4; i++){
      a[2*i]   = sw * bf2f(w[i] & 0xffff);
      a[2*i+1] = sw * bf2f(w[i] >> 16);
    }
  }
  int e = rs;
  for (; e + 1 < re; e += 2){
    int s0 = cols[e], s1 = cols[e+1];
    float v0 = vals[e], v1 = vals[e+1];
    uint4 q0 = *(const uint4*)&Hg[((size_t)s0 * 32 + batch) * 512 + f8];
    uint4 q1 = *(const uint4*)&Hg[((size_t)s1 * 32 + batch) * 512 + f8];
    const unsigned int* w0 = (const unsigned int*)&q0;
    const unsigned int* w1 = (const unsigned int*)&q1;
    #pragma unroll
    for (int i = 0; i < 4; i++){
      a[2*i]   += v0 * bf2f(w0[i] & 0xffff) + v1 * bf2f(w1[i] & 0xffff);
      a[2*i+1] += v0 * bf2f(w0[i] >> 16)    + v1 * bf2f(w1[i] >> 16);
    }
  }
  if (e < re){
    int s = cols[e]; float v = vals[e];
    uint4 q = *(const uint4*)&Hg[((size_t)s * 32 + batch) * 512 + f8];
    const unsigned int* w = (const unsigned int*)&q;
    #pragma unroll
    for (int i = 0; i < 4; i++){
      a[2*i]   += v * bf2f(w[i] & 0xffff);
      a[2*i+1] += v * bf2f(w[i] >> 16);
    }
  }
  unsigned int o[4];
  #pragma unroll
  for (int i = 0; i < 4; i++)
    o[i] = (unsigned int)f2bf(a[2*i]) | ((unsigned int)f2bf(a[2*i+1]) << 16);
  *(uint4*)&Xo[((size_t)dst * 32 + batch) * 512 + f8] = *(uint4*)o;
}

// ---------------- bf16 MFMA GEMM: A AND B double-buffered via global_load_lds, 1 barrier/iter ----------------
template<int BM, int BN, int WM, int WN, int TM, int TN>
__global__ __launch_bounds__(WM*WN*64) void k_gemm(
    const unsigned short* __restrict__ Xg, const unsigned short* __restrict__ Wt,
    unsigned short* __restrict__ Hg, int K, int N,
    const float* __restrict__ wsumv, const float* __restrict__ cvec,
    const float* __restrict__ bias, int relu){
  constexpr int BK = 32;
  constexpr int NW = WM * WN;
  constexpr int RA = BM / NW;
  constexpr int RB = BN / NW;
  __shared__ __align__(16) unsigned short As[2][BM * BK];
  __shared__ __align__(16) unsigned short Bs[2][BN * BK];
  const int tid = threadIdx.x;
  const int row0 = blockIdx.x * BM, col0 = blockIdx.y * BN;
  const int wave = tid >> 6, lane = tid & 63;
  const int wr = wave / WN, wc = wave % WN;
  const int lrow = lane & 15, lq = lane >> 4;
  const int lrw = lane >> 2, lcol = (lane & 3) * 8;
  const int arow = wave * RA, brow = wave * RB;
  f32x4 acc[TM][TN] = {};
  #pragma unroll
  for (int t = 0; t < RA / 16; t++)
    gload16(&Xg[(size_t)(row0 + arow + t * 16 + lrw) * K + lcol],
            &As[0][(arow + t * 16) * BK]);
  #pragma unroll
  for (int t = 0; t < RB / 16; t++)
    gload16(&Wt[(size_t)(col0 + brow + t * 16 + lrw) * K + lcol],
            &Bs[0][(brow + t * 16) * BK]);
  int cur = 0;
  for (int k0 = 0; k0 < K; k0 += BK){
    __syncthreads();
    if (k0 + BK < K){
      #pragma unroll
      for (int t = 0; t < RA / 16; t++)
        gload16(&Xg[(size_t)(row0 + arow + t * 16 + lrw) * K + k0 + BK + lcol],
                &As[cur ^ 1][(arow + t * 16) * BK]);
      #pragma unroll
      for (int t = 0; t < RB / 16; t++)
        gload16(&Wt[(size_t)(col0 + brow + t * 16 + lrw) * K + k0 + BK + lcol],
                &Bs[cur ^ 1][(brow + t * 16) * BK]);
    }
    bf16x8 af[TM], bfr[TN];
    #pragma unroll
    for (int tm = 0; tm < TM; tm++)
      af[tm] = *(const bf16x8*)&As[cur][(wr * TM * 16 + tm * 16 + lrow) * BK + lq * 8];
    #pragma unroll
    for (int tn = 0; tn < TN; tn++)
      bfr[tn] = *(const bf16x8*)&Bs[cur][(wc * TN * 16 + tn * 16 + lrow) * BK + lq * 8];
    #pragma unroll
    for (int tm = 0; tm < TM; tm++)
      #pragma unroll
      for (int tn = 0; tn < TN; tn++)
        acc[tm][tn] = __builtin_amdgcn_mfma_f32_16x16x32_bf16(af[tm], bfr[tn], acc[tm][tn], 0, 0, 0);
    cur ^= 1;
  }
  #pragma unroll
  for (int tm = 0; tm < TM; tm++){
    #pragma unroll
    for (int tn = 0; tn < TN; tn++){
      int col = col0 + wc * TN * 16 + tn * 16 + lrow;
      float cv = 0.f, bv = 0.f;
      if (cvec){ cv = cvec[col]; bv = bias[col]; }
      #pragma unroll
      for (int r = 0; r < 4; r++){
        int row = row0 + wr * TM * 16 + tm * 16 + lq * 4 + r;
        float x = acc[tm][tn][r];
        if (cvec) x += wsumv[row >> 5] * cv + bv;
        if (relu) x = fmaxf(x, 0.f);
        Hg[(size_t)row * N + col] = f2bf(x);
      }
    }
  }
}

// ---------------- h5 = x4 @ W56 (K=512,N=3): grid-wide wave/row, batch-major out ----------------
__global__ __launch_bounds__(256) void k_h5(
    const unsigned short* __restrict__ x4, const float* __restrict__ W56,
    float* __restrict__ h5){
  int m = blockIdx.x * 4 + (threadIdx.x >> 6);   // vertex-major row m = v*32+b
  int lane = threadIdx.x & 63;
  uint4 q = *(const uint4*)&x4[(size_t)m * 512 + lane * 8];
  const unsigned int* w = (const unsigned int*)&q;
  float a0 = 0.f, a1 = 0.f, a2 = 0.f;
  #pragma unroll
  for (int i = 0; i < 8; i++){
    float x = bf2f((i & 1) ? (unsigned short)(w[i >> 1] >> 16)
                           : (unsigned short)(w[i >> 1] & 0xffff));
    int k = lane * 8 + i;
    a0 += x * W56[k * 3]; a1 += x * W56[k * 3 + 1]; a2 += x * W56[k * 3 + 2];
  }
  #pragma unroll
  for (int off = 32; off; off >>= 1){
    a0 += __shfl_down(a0, off);
    a1 += __shfl_down(a1, off);
    a2 += __shfl_down(a2, off);
  }
  if (lane == 0){
    int v = m >> 5, b = m & 31;
    float* o = h5 + ((size_t)b * V_ + v) * 3;    // batch-major out
    o[0] = a0; o[1] = a1; o[2] = a2;
  }
}

// ---------------- k_xa2: per-batch A^2 on F=3 + epilogue (tiny LDS tile) ----------------
__global__ __launch_bounds__(1024) void k_xa2(
    const float* __restrict__ in, const int* __restrict__ rowptr,
    const int* __restrict__ cols, const float* __restrict__ vals,
    const float* __restrict__ selfw, const float* __restrict__ wsum,
    const float* __restrict__ C56, const float* __restrict__ b6,
    float* __restrict__ XF){
  __shared__ float xs[V_ * 3];
  __shared__ float ys[V_ * 3];
  int b = blockIdx.x, t = threadIdx.x;
  const float* ib = in + (size_t)b * V_ * 3;
  for (int i = t; i < V_ * 3; i += 1024) xs[i] = ib[i];
  __syncthreads();
  for (int v = t; v < V_; v += 1024){
    float sw = selfw[v];
    float a0 = sw * xs[v*3], a1 = sw * xs[v*3+1], a2 = sw * xs[v*3+2];
    int re = rowptr[v + 1];
    for (int e = rowptr[v]; e < re; e++){
      int s = cols[e]; float vv = vals[e];
      a0 += vv * xs[s*3]; a1 += vv * xs[s*3+1]; a2 += vv * xs[s*3+2];
    }
    ys[v*3] = a0; ys[v*3+1] = a1; ys[v*3+2] = a2;
  }
  __syncthreads();
  float* ob = XF + (size_t)b * V_ * 3;
  for (int v = t; v < V_; v += 1024){
    float sw = selfw[v];
    float a0 = sw * ys[v*3], a1 = sw * ys[v*3+1], a2 = sw * ys[v*3+2];
    int re = rowptr[v + 1];
    for (int e = rowptr[v]; e < re; e++){
      int s = cols[e]; float vv = vals[e];
      a0 += vv * ys[s*3]; a1 += vv * ys[s*3+1]; a2 += vv * ys[s*3+2];
    }
    float w = wsum[v];
    a0 = fmaxf(a0 + w * C56[0] + b6[0], 0.f);
    a1 = fmaxf(a1 + w * C56[1] + b6[1], 0.f);
    a2 = fmaxf(a2 + w * C56[2] + b6[2], 0.f);
    ob[v*3] = a0; ob[v*3+1] = a1; ob[v*3+2] = a2;
  }
}

// ---------------- FC split-K stage A ----------------
template<int R, int KC>
__global__ __launch_bounds__(256) void k_fcp(
    const float* __restrict__ in, const float* __restrict__ W,
    float* __restrict__ partial, int K, int N){
  const int n = blockIdx.x * 256 + threadIdx.x;
  const int k0 = blockIdx.y * KC;
  float acc[R] = {};
  for (int kk = 0; kk < KC; kk += 4){
    const float* wp = W + (size_t)(k0 + kk) * N + n;
    float w0 = wp[0];
    float w1 = wp[(size_t)N];
    float w2 = wp[(size_t)2 * N];
    float w3 = wp[(size_t)3 * N];
    #pragma unroll
    for (int r = 0; r < R; r++){
      const float* xp = in + (size_t)r * K + k0 + kk;
      acc[r] += xp[0]*w0 + xp[1]*w1 + xp[2]*w2 + xp[3]*w3;
    }
  }
  float* p = partial + (size_t)blockIdx.y * R * N + n;
  #pragma unroll
  for (int r = 0; r < R; r++) p[(size_t)r * N] = acc[r];
}

// ---------------- FC split-K stage B ----------------
__global__ __launch_bounds__(256) void k_fcr(
    const float* __restrict__ partial, const float* __restrict__ bias,
    float* __restrict__ out, int total, int N, int KS, int mode,
    const float* __restrict__ vert){
  int id = blockIdx.x * 256 + threadIdx.x;
  if (id >= total) return;
  int n = id % N;
  float a0 = 0.f, a1 = 0.f, a2 = 0.f, a3 = 0.f;
  int s = 0;
  for (; s + 4 <= KS; s += 4){
    a0 += partial[(size_t)s * total + id];
    a1 += partial[(size_t)(s + 1) * total + id];
    a2 += partial[(size_t)(s + 2) * total + id];
    a3 += partial[(size_t)(s + 3) * total + id];
  }
  for (; s < KS; s++) a0 += partial[(size_t)s * total + id];
  float acc = a0 + a1 + a2 + a3;
  if (bias) acc += bias[n];
  if (mode) acc = vert[id] + 0.1f * tanhf(acc);
  out[id] = acc;
}

// ---------------- workspace layout ----------------
static constexpr size_t AL(size_t x){ return (x + 255) & ~(size_t)255; }
static constexpr size_t S512 = (size_t)M_ * 512 * 2;
static constexpr size_t S3   = (size_t)M_ * 3 * 4;
static constexpr size_t OXA  = 0;
static constexpr size_t OXB  = OXA  + AL(S512);
static constexpr size_t OVA2 = OXB  + AL(S512);
static constexpr size_t OH5  = OVA2 + AL(S3);
static constexpr size_t OXF  = OH5  + AL(S3);
static constexpr size_t OFC1 = OXF  + AL(S3);
static constexpr size_t OFC2 = OFC1 + AL((size_t)B_ * 1024 * 4);
static constexpr size_t OI1  = OFC2 + AL((size_t)B_ * 1024 * 4);
static constexpr size_t OP   = OI1  + AL((size_t)32 * 512 * 4);
static constexpr size_t OC34 = OP   + AL((size_t)36 * 512 * 4);
static constexpr size_t OW56 = OC34 + AL((size_t)512 * 4);
static constexpr size_t OC56 = OW56 + AL((size_t)512 * 3 * 4);
static constexpr size_t OW3B = OC56 + AL((size_t)3 * 4);
static constexpr size_t OW4T = OW3B + AL((size_t)512 * 512 * 2);
static constexpr size_t OW34 = OW4T + AL((size_t)512 * 512 * 2);
static constexpr size_t OROW = OW34 + AL((size_t)512 * 512 * 2);
static constexpr size_t OCOL = OROW + AL((size_t)(V_ + 1) * 4);
static constexpr size_t OVAL = OCOL + AL((size_t)E_ * 4);
static constexpr size_t OSELF= OVAL + AL((size_t)E_ * 4);
static constexpr size_t OWS  = OSELF+ AL((size_t)V_ * 4);
static constexpr size_t OW2S = OWS  + AL((size_t)V_ * 4);

extern "C" void kernel_launch(void* const* d_in, const int* in_sizes, int n_in,
                              void* d_out, int out_size, void* d_ws, size_t ws_size,
                              hipStream_t stream){
  const float* vert  = (const float*)d_in[0];
  const float* img   = (const float*)d_in[1];
  const int*   ei    = (const int*)  d_in[2];
  const float* W1 = (const float*)d_in[3],  *b1 = (const float*)d_in[4];
  const float* W2 = (const float*)d_in[5],  *b2 = (const float*)d_in[6];
  const float* W3 = (const float*)d_in[7],  *b3 = (const float*)d_in[8];
  const float* W4 = (const float*)d_in[9],  *b4 = (const float*)d_in[10];
  const float* W5 = (const float*)d_in[11], *b5 = (const float*)d_in[12];
  const float* W6 = (const float*)d_in[13], *b6 = (const float*)d_in[14];
  const float* fcW1 = (const float*)d_in[15], *fcb1 = (const float*)d_in[16];
  const float* fcW2 = (const float*)d_in[17], *fcb2 = (const float*)d_in[18];
  const float* fcW3 = (const float*)d_in[19], *fcb3 = (const float*)d_in[20];
  float* out = (float*)d_out;

  char* ws = (char*)d_ws;
  unsigned short* XA  = (unsigned short*)(ws + OXA);
  unsigned short* XB  = (unsigned short*)(ws + OXB);
  float* VA2v = (float*)(ws + OVA2);
  float* H5   = (float*)(ws + OH5);
  float* XF   = (float*)(ws + OXF);
  float* FC1o = (float*)(ws + OFC1);
  float* FC2o = (float*)(ws + OFC2);
  float* I1   = (float*)(ws + OI1);
  float* P    = (float*)(ws + OP);
  float* C34  = (float*)(ws + OC34);
  float* W56  = (float*)(ws + OW56);
  float* C56  = (float*)(ws + OC56);
  unsigned short* W3B = (unsigned short*)(ws + OW3B);
  unsigned short* W4T = (unsigned short*)(ws + OW4T);
  unsigned short* W34 = (unsigned short*)(ws + OW34);
  float* PARTA = (float*)(ws + OXA);
  float* PARTB = (float*)(ws + OXB);
  int*   ROW  = (int*)(ws + OROW);
  int*   COL  = (int*)(ws + OCOL);
  float* VAL  = (float*)(ws + OVAL);
  float* SELF = (float*)(ws + OSELF);
  float* WSUM = (float*)(ws + OWS);
  float* W2S  = (float*)(ws + OW2S);

  // ---- CSR + norm powers ----
  k_csr<<<1, 1024, 0, stream>>>(ei, ROW, COL, VAL, SELF, WSUM, W2S);

  // ---- precompute ----
  k_preA<<<256 + 1024 + 16, 256, 0, stream>>>(W3, W4, img, W1, W3B, W4T, PARTB);
  k_preB<<<64 + 9, 256, 0, stream>>>(PARTB, I1, b3, W4, W5, W6, b5, C34, W56, C56);
  k_preC<<<16, 256, 0, stream>>>(b1, W1, I1, W2, PARTB);
  k_preD<<<72, 256, 0, stream>>>(PARTB, P);
  k_gemm<64,64,2,2,2,2><<<dim3(8, 8), 256, 0, stream>>>(W4T, W3B, W34, 512, 512,
                                                        nullptr, nullptr, nullptr, 0);

  // ---- layers 1-3a: VA2 (vertex-major), then fused x2+A-hop ----
  k_va2<<<B_, 1024, 0, stream>>>(vert, ROW, COL, VAL, SELF, VA2v);
  k_y1<<<dim3(V_, 8), 256, 0, stream>>>(VA2v, P, WSUM, W2S, b2, ROW, COL, VAL, SELF, XB);

  // ---- second A-hop + GEMM w/ fused epilogue ----
  k_aggb<<<dim3(V_, 8), 256, 0, stream>>>(XB, ROW, COL, VAL, SELF, XA);
  k_gemm<128,128,2,2,4,4><<<dim3(M_ / 128, 4), 256, 0, stream>>>(XA, W34, XB, 512, 512,
                                                                 WSUM, C34, b4, 1);

  // ---- layers 5+6: grid-wide skinny GEMM, then per-batch A^2 (F=3) + epilogue ----
  k_h5<<<M_ / 4, 256, 0, stream>>>(XB, W56, H5);
  k_xa2<<<B_, 1024, 0, stream>>>(H5, ROW, COL, VAL, SELF, WSUM, C56, b6, XF);

  // ---- FC head ----
  k_fcp<32,64><<<dim3(4, 96), 256, 0, stream>>>(XF, fcW1, PARTA, 6144, 1024);
  k_fcr<<<(B_ * 1024 + 255) / 256, 256, 0, stream>>>(PARTA, fcb1, FC1o, 32 * 1024, 1024, 96, 0, nullptr);
  k_fcp<32,64><<<dim3(4, 16), 256, 0, stream>>>(FC1o, fcW2, PARTA, 1024, 1024);
  k_fcr<<<(B_ * 1024 + 255) / 256, 256, 0, stream>>>(PARTA, fcb2, FC2o, 32 * 1024, 1024, 16, 0, nullptr);
  k_fcp<32,64><<<dim3(24, 16), 256, 0, stream>>>(FC2o, fcW3, PARTA, 1024, 6144);
  k_fcr<<<(B_ * 6144 + 255) / 256, 256, 0, stream>>>(PARTA, fcb3, out, 32 * 6144, 6144, 16, 1, vert);
}

// Round 9
// 617.234 us; speedup vs baseline: 1.2186x; 1.0201x over previous
//
#include <hip/hip_runtime.h>
#include <stdint.h>
#include <math.h>

#define B_ 32
#define V_ 2048
#define E_ 12288
#define M_ (B_*V_)

typedef __bf16 bf16x8 __attribute__((ext_vector_type(8)));
typedef float f32x4 __attribute__((ext_vector_type(4)));

__device__ __forceinline__ float bf2f(unsigned short u){
  union { unsigned int i; float f; } v; v.i = ((unsigned int)u) << 16; return v.f;
}
__device__ __forceinline__ unsigned short f2bf(float f){
  union { float f; unsigned int i; } v; v.f = f;
  unsigned int r = (v.i + 0x7fffu + ((v.i >> 16) & 1u)) >> 16;
  return (unsigned short)r;
}
__device__ __forceinline__ void gload16(const unsigned short* g, unsigned short* l){
  __builtin_amdgcn_global_load_lds(
      (const __attribute__((address_space(1))) void*)g,
      (__attribute__((address_space(3))) void*)l, 16, 0, 0);
}

// ---------------- k_pre0: block 0 = CSR build (1024 thr); blocks 1.. = preA work ----------------
__global__ __launch_bounds__(1024) void k_pre0(
    const int* __restrict__ ei, int* __restrict__ rowptr_g, int* __restrict__ cols_g,
    float* __restrict__ vals_g, float* __restrict__ selfw_g,
    float* __restrict__ wsum_g, float* __restrict__ w2_g,
    const float* __restrict__ W3, const float* __restrict__ W4,
    const float* __restrict__ img, const float* __restrict__ W1,
    unsigned short* __restrict__ W3B, unsigned short* __restrict__ W4T,
    float* __restrict__ partB){
  __shared__ int   sdeg[V_];
  __shared__ int   srp[V_ + 1];
  __shared__ int   sfill[V_];
  __shared__ float sdinv[V_];
  __shared__ float swsum[V_];
  __shared__ float sw2[V_];
  __shared__ int   swt[16];
  __shared__ float tile[4][32][33];
  if (blockIdx.x == 0){
    const int t = threadIdx.x;
    sdeg[2*t] = 0; sdeg[2*t+1] = 0; sfill[2*t] = 0; sfill[2*t+1] = 0;
    __syncthreads();
    #pragma unroll
    for (int e = t; e < E_; e += 1024) atomicAdd(&sdeg[ei[E_ + e]], 1);
    __syncthreads();
    int c0 = sdeg[2*t], c1 = sdeg[2*t+1];
    int s2 = c0 + c1;
    int lane = t & 63, wid = t >> 6;
    int pre = s2;
    #pragma unroll
    for (int off = 1; off < 64; off <<= 1){
      int u = __shfl_up(pre, off);
      if (lane >= off) pre += u;
    }
    if (lane == 63) swt[wid] = pre;
    __syncthreads();
    if (t == 0){
      int run = 0;
      #pragma unroll
      for (int i = 0; i < 16; i++){ int x = swt[i]; swt[i] = run; run += x; }
      srp[V_] = run;
    }
    __syncthreads();
    int base = swt[wid] + (pre - s2);
    srp[2*t] = base; srp[2*t+1] = base + c0;
    #pragma unroll
    for (int v = t; v < V_; v += 1024){
      float d = (float)(sdeg[v] + 1);
      float di = rsqrtf(d);
      sdinv[v] = di;
      swsum[v] = di * di;
    }
    __syncthreads();
    #pragma unroll
    for (int e = t; e < E_; e += 1024){
      int s = ei[e], d = ei[E_ + e];
      int pos = srp[d] + atomicAdd(&sfill[d], 1);
      float val = sdinv[s] * sdinv[d];
      cols_g[pos] = s;
      vals_g[pos] = val;
      atomicAdd(&swsum[d], val);
    }
    __syncthreads();
    #pragma unroll
    for (int v = t; v < V_; v += 1024)
      sw2[v] = (sdinv[v] * sdinv[v]) * swsum[v];
    __syncthreads();
    #pragma unroll
    for (int e = t; e < E_; e += 1024){
      int s = ei[e], d = ei[E_ + e];
      atomicAdd(&sw2[d], sdinv[s] * sdinv[d] * swsum[s]);
    }
    __syncthreads();
    #pragma unroll
    for (int v = t; v < V_; v += 1024){
      rowptr_g[v] = srp[v];
      selfw_g[v]  = sdinv[v] * sdinv[v];
      wsum_g[v]   = swsum[v];
      w2_g[v]     = sw2[v];
    }
    if (t == 0) rowptr_g[V_] = srp[V_];
  } else {
    // preA: 4 sub-blocks of 256 threads each; region boundaries are 4-aligned
    int u = blockIdx.x - 1;
    int t10 = threadIdx.x;
    int sub = (u << 2) + (t10 >> 8);
    int t = t10 & 255;
    int ti = t10 >> 8;
    if (sub < 256){
      int tr0 = (sub >> 4) << 5, tc0 = (sub & 15) << 5;
      int r = t >> 5, c = t & 31;
      #pragma unroll
      for (int i = 0; i < 4; i++)
        tile[ti][r + 8*i][c] = W4[(size_t)(tr0 + r + 8*i) * 512 + tc0 + c];
      __syncthreads();
      #pragma unroll
      for (int i = 0; i < 4; i++)
        W4T[(size_t)(tc0 + r + 8*i) * 512 + tr0 + c] = f2bf(tile[ti][c][r + 8*i]);
    } else if (sub < 256 + 1024){
      int id = (sub - 256) * 256 + t;
      W3B[id] = f2bf(W3[id]);
    } else {
      int bx = sub - 1280;
      int n = ((bx & 1) << 8) + t;
      int k0 = (bx >> 1) * 64;
      const float* W = W1 + 3 * 512;
      float acc[32] = {};
      for (int kk = 0; kk < 64; kk += 4){
        const float* wp = W + (size_t)(k0 + kk) * 512 + n;
        float w0 = wp[0], w1 = wp[512], w2 = wp[1024], w3 = wp[1536];
        #pragma unroll
        for (int r = 0; r < 32; r++){
          const float* xp = img + (size_t)r * 512 + k0 + kk;
          acc[r] += xp[0]*w0 + xp[1]*w1 + xp[2]*w2 + xp[3]*w3;
        }
      }
      float* p = partB + (size_t)(bx >> 1) * 32 * 512 + n;
      #pragma unroll
      for (int r = 0; r < 32; r++) p[(size_t)r * 512] = acc[r];
    }
  }
}

// ---------------- preB: I1 reduce + small weight products ----------------
__global__ __launch_bounds__(256) void k_preB(
    const float* __restrict__ partB, float* __restrict__ I1,
    const float* __restrict__ b3, const float* __restrict__ W4,
    const float* __restrict__ W5, const float* __restrict__ W6,
    const float* __restrict__ b5,
    float* __restrict__ C34, float* __restrict__ W56, float* __restrict__ C56){
  int blk = blockIdx.x, t = threadIdx.x;
  if (blk < 64){
    int id = blk * 256 + t;
    float a = 0.f;
    #pragma unroll
    for (int s = 0; s < 8; s++) a += partB[(size_t)s * 16384 + id];
    I1[id] = a;
  } else {
    int id = (blk - 64) * 256 + t;
    if (id < 512){
      float a0=0,a1=0,a2=0,a3=0;
      for (int k = 0; k < 512; k += 4){
        a0 += b3[k]   * W4[(size_t)k * 512 + id];
        a1 += b3[k+1] * W4[(size_t)(k+1) * 512 + id];
        a2 += b3[k+2] * W4[(size_t)(k+2) * 512 + id];
        a3 += b3[k+3] * W4[(size_t)(k+3) * 512 + id];
      }
      C34[id] = a0+a1+a2+a3;
    } else if (id < 512 + 1536){
      int i = id - 512; int k5 = i / 3, j = i % 3;
      float a = 0.f;
      #pragma unroll 4
      for (int u = 0; u < 64; u++) a += W5[k5 * 64 + u] * W6[u * 3 + j];
      W56[i] = a;
    } else if (id < 512 + 1536 + 3){
      int j = id - (512 + 1536);
      float a = 0.f;
      #pragma unroll 4
      for (int u = 0; u < 64; u++) a += b5[u] * W6[u * 3 + j];
      C56[j] = a;
    }
  }
}

// ---------------- preC: P split-K partials, inline CAT = [b1; W1 rows 0-2; I1] ----------------
__global__ __launch_bounds__(256) void k_preC(
    const float* __restrict__ b1, const float* __restrict__ W1,
    const float* __restrict__ I1, const float* __restrict__ W2,
    float* __restrict__ partB){
  int bx = blockIdx.x;
  int n = ((bx & 1) << 8) + threadIdx.x;
  int k0 = (bx >> 1) * 64;
  float acc[36] = {};
  for (int kk = 0; kk < 64; kk += 4){
    int k = k0 + kk;
    const float* wp = W2 + (size_t)k * 512 + n;
    float w0 = wp[0], w1 = wp[512], w2 = wp[1024], w3 = wp[1536];
    #pragma unroll
    for (int r = 0; r < 36; r++){
      const float* q;
      if (r == 0)      q = b1 + k;
      else if (r < 4)  q = W1 + (size_t)(r - 1) * 512 + k;
      else             q = I1 + (size_t)(r - 4) * 512 + k;
      acc[r] += q[0]*w0 + q[1]*w1 + q[2]*w2 + q[3]*w3;
    }
  }
  float* p = partB + (size_t)(bx >> 1) * 36 * 512 + n;
  #pragma unroll
  for (int r = 0; r < 36; r++) p[(size_t)r * 512] = acc[r];
}

// ---------------- preD: P reduce ----------------
__global__ __launch_bounds__(256) void k_preD(
    const float* __restrict__ partB, float* __restrict__ P){
  int id = blockIdx.x * 256 + threadIdx.x;
  float a = 0.f;
  #pragma unroll
  for (int s = 0; s < 8; s++) a += partB[(size_t)s * 18432 + id];
  P[id] = a;
}

// ---------------- VA2 = A^2 vert, per-batch LDS double hop; OUTPUT VERTEX-MAJOR ----------------
__global__ __launch_bounds__(1024) void k_va2(
    const float* __restrict__ in, const int* __restrict__ rowptr,
    const int* __restrict__ cols, const float* __restrict__ vals,
    const float* __restrict__ selfw, float* __restrict__ outv){
  __shared__ float xs[V_ * 3];
  __shared__ float ys[V_ * 3];
  int b = blockIdx.x, t = threadIdx.x;
  const float* ib = in + (size_t)b * V_ * 3;
  for (int i = t; i < V_ * 3; i += 1024) xs[i] = ib[i];
  __syncthreads();
  for (int v = t; v < V_; v += 1024){
    float sw = selfw[v];
    float a0 = sw * xs[v*3], a1 = sw * xs[v*3+1], a2 = sw * xs[v*3+2];
    int re = rowptr[v + 1];
    for (int e = rowptr[v]; e < re; e++){
      int s = cols[e]; float vv = vals[e];
      a0 += vv * xs[s*3]; a1 += vv * xs[s*3+1]; a2 += vv * xs[s*3+2];
    }
    ys[v*3] = a0; ys[v*3+1] = a1; ys[v*3+2] = a2;
  }
  __syncthreads();
  for (int v = t; v < V_; v += 1024){
    float sw = selfw[v];
    float a0 = sw * ys[v*3], a1 = sw * ys[v*3+1], a2 = sw * ys[v*3+2];
    int re = rowptr[v + 1];
    for (int e = rowptr[v]; e < re; e++){
      int s = cols[e]; float vv = vals[e];
      a0 += vv * ys[s*3]; a1 += vv * ys[s*3+1]; a2 += vv * ys[s*3+2];
    }
    float* o = outv + ((size_t)v * 32 + b) * 3;
    o[0] = a0; o[1] = a1; o[2] = a2;
  }
}

// ---------------- k_y1: fused x2-on-the-fly + A-hop. Y1[dst][b][f] (vertex-major bf16) ----------------
__global__ __launch_bounds__(256) void k_y1(
    const float* __restrict__ va2v, const float* __restrict__ P,
    const float* __restrict__ wsum, const float* __restrict__ w2s,
    const float* __restrict__ b2,
    const int* __restrict__ rowptr, const int* __restrict__ cols,
    const float* __restrict__ vals, const float* __restrict__ selfw,
    unsigned short* __restrict__ Y){
  int dst = blockIdx.x;
  int batch = (blockIdx.y << 2) + (threadIdx.x >> 6);
  int f8 = (threadIdx.x & 63) * 8;
  float wv0[8], wv1[8], wv2[8], cc[8], bb[8], ii[8];
  #pragma unroll
  for (int j = 0; j < 8; j++){
    int fc = f8 + j;
    wv0[j] = P[512 + fc]; wv1[j] = P[1024 + fc]; wv2[j] = P[1536 + fc];
    cc[j]  = P[fc];       bb[j]  = b2[fc];
    ii[j]  = P[2048 + (size_t)batch * 512 + fc];
  }
  float acc[8] = {};
  int rs = rowptr[dst], re = rowptr[dst + 1];
  for (int e = rs - 1; e < re; e++){
    int s; float w;
    if (e < rs){ s = dst; w = selfw[dst]; }
    else       { s = cols[e]; w = vals[e]; }
    const float* va = va2v + ((size_t)s * 32 + batch) * 3;
    float x0 = va[0], x1 = va[1], x2 = va[2];
    float w2v = w2s[s], wsv = wsum[s];
    #pragma unroll
    for (int j = 0; j < 8; j++){
      float tv = x0*wv0[j] + x1*wv1[j] + x2*wv2[j] + w2v*ii[j] + wsv*cc[j] + bb[j];
      tv = fmaxf(tv, 0.f);
      acc[j] += w * tv;
    }
  }
  unsigned int o[4];
  #pragma unroll
  for (int i = 0; i < 4; i++)
    o[i] = (unsigned int)f2bf(acc[2*i]) | ((unsigned int)f2bf(acc[2*i+1]) << 16);
  *(uint4*)&Y[((size_t)dst * 32 + batch) * 512 + f8] = *(uint4*)o;
}

// ---------------- F=512 bf16 aggregation, vertex-major, wave-per-batch, edge-unroll x2 ----------------
__global__ __launch_bounds__(256) void k_aggb(
    const unsigned short* __restrict__ Hg, const int* __restrict__ rowptr,
    const int* __restrict__ cols, const float* __restrict__ vals,
    const float* __restrict__ selfw, unsigned short* __restrict__ Xo){
  int dst = blockIdx.x;
  int batch = (blockIdx.y << 2) + (threadIdx.x >> 6);
  int f8 = (threadIdx.x & 63) * 8;
  int rs = rowptr[dst], re = rowptr[dst + 1];
  float sw = selfw[dst];
  float a[8];
  {
    uint4 q = *(const uint4*)&Hg[((size_t)dst * 32 + batch) * 512 + f8];
    const unsigned int* w = (const unsigned int*)&q;
    #pragma unroll
    for (int i = 0; i < 4; i++){
      a[2*i]   = sw * bf2f(w[i] & 0xffff);
      a[2*i+1] = sw * bf2f(w[i] >> 16);
    }
  }
  int e = rs;
  for (; e + 1 < re; e += 2){
    int s0 = cols[e], s1 = cols[e+1];
    float v0 = vals[e], v1 = vals[e+1];
    uint4 q0 = *(const uint4*)&Hg[((size_t)s0 * 32 + batch) * 512 + f8];
    uint4 q1 = *(const uint4*)&Hg[((size_t)s1 * 32 + batch) * 512 + f8];
    const unsigned int* w0 = (const unsigned int*)&q0;
    const unsigned int* w1 = (const unsigned int*)&q1;
    #pragma unroll
    for (int i = 0; i < 4; i++){
      a[2*i]   += v0 * bf2f(w0[i] & 0xffff) + v1 * bf2f(w1[i] & 0xffff);
      a[2*i+1] += v0 * bf2f(w0[i] >> 16)    + v1 * bf2f(w1[i] >> 16);
    }
  }
  if (e < re){
    int s = cols[e]; float v = vals[e];
    uint4 q = *(const uint4*)&Hg[((size_t)s * 32 + batch) * 512 + f8];
    const unsigned int* w = (const unsigned int*)&q;
    #pragma unroll
    for (int i = 0; i < 4; i++){
      a[2*i]   += v * bf2f(w[i] & 0xffff);
      a[2*i+1] += v * bf2f(w[i] >> 16);
    }
  }
  unsigned int o[4];
  #pragma unroll
  for (int i = 0; i < 4; i++)
    o[i] = (unsigned int)f2bf(a[2*i]) | ((unsigned int)f2bf(a[2*i+1]) << 16);
  *(uint4*)&Xo[((size_t)dst * 32 + batch) * 512 + f8] = *(uint4*)o;
}

// ---------------- bf16 MFMA GEMM, A/B dbuf via global_load_lds, 1 barrier/iter ----------------
// If h5p != null: fused epilogue computes relu(acc + wsum*cvec + bias) and contracts the
// block's 128-col slice with W56 (512x3) -> per-block fp32 partial H5P[blockIdx.y][m][3].
// No x4 is written at all. Otherwise: writes Hg bf16 (plain, cvec==null path for W34 product).
template<int BM, int BN, int WM, int WN, int TM, int TN>
__global__ __launch_bounds__(WM*WN*64) void k_gemm(
    const unsigned short* __restrict__ Xg, const unsigned short* __restrict__ Wt,
    unsigned short* __restrict__ Hg, int K, int N,
    const float* __restrict__ wsumv, const float* __restrict__ cvec,
    const float* __restrict__ bias, int relu,
    const float* __restrict__ W56g, float* __restrict__ h5p){
  constexpr int BK = 32;
  constexpr int NW = WM * WN;
  constexpr int NT = NW * 64;
  constexpr int RA = BM / NW;
  constexpr int RB = BN / NW;
  __shared__ __align__(16) unsigned short As[2][BM * BK];
  __shared__ __align__(16) unsigned short Bs[2][BN * BK];
  __shared__ float h5s[BM * 3];
  const int tid = threadIdx.x;
  const int row0 = blockIdx.x * BM, col0 = blockIdx.y * BN;
  const int wave = tid >> 6, lane = tid & 63;
  const int wr = wave / WN, wc = wave % WN;
  const int lrow = lane & 15, lq = lane >> 4;
  const int lrw = lane >> 2, lcol = (lane & 3) * 8;
  const int arow = wave * RA, brow = wave * RB;
  if (h5p){
    for (int i = tid; i < BM * 3; i += NT) h5s[i] = 0.f;
  }
  f32x4 acc[TM][TN] = {};
  #pragma unroll
  for (int t = 0; t < RA / 16; t++)
    gload16(&Xg[(size_t)(row0 + arow + t * 16 + lrw) * K + lcol],
            &As[0][(arow + t * 16) * BK]);
  #pragma unroll
  for (int t = 0; t < RB / 16; t++)
    gload16(&Wt[(size_t)(col0 + brow + t * 16 + lrw) * K + lcol],
            &Bs[0][(brow + t * 16) * BK]);
  int cur = 0;
  for (int k0 = 0; k0 < K; k0 += BK){
    __syncthreads();
    if (k0 + BK < K){
      #pragma unroll
      for (int t = 0; t < RA / 16; t++)
        gload16(&Xg[(size_t)(row0 + arow + t * 16 + lrw) * K + k0 + BK + lcol],
                &As[cur ^ 1][(arow + t * 16) * BK]);
      #pragma unroll
      for (int t = 0; t < RB / 16; t++)
        gload16(&Wt[(size_t)(col0 + brow + t * 16 + lrw) * K + k0 + BK + lcol],
                &Bs[cur ^ 1][(brow + t * 16) * BK]);
    }
    bf16x8 af[TM], bfr[TN];
    #pragma unroll
    for (int tm = 0; tm < TM; tm++)
      af[tm] = *(const bf16x8*)&As[cur][(wr * TM * 16 + tm * 16 + lrow) * BK + lq * 8];
    #pragma unroll
    for (int tn = 0; tn < TN; tn++)
      bfr[tn] = *(const bf16x8*)&Bs[cur][(wc * TN * 16 + tn * 16 + lrow) * BK + lq * 8];
    #pragma unroll
    for (int tm = 0; tm < TM; tm++)
      #pragma unroll
      for (int tn = 0; tn < TN; tn++)
        acc[tm][tn] = __builtin_amdgcn_mfma_f32_16x16x32_bf16(af[tm], bfr[tn], acc[tm][tn], 0, 0, 0);
    cur ^= 1;
  }
  if (h5p){
    // fused epilogue: relu(acc + wsum*cv + bv) . W56-slice -> block partial
    float w56l[TN][3], cvl[TN], bvl[TN];
    #pragma unroll
    for (int tn = 0; tn < TN; tn++){
      int col = col0 + wc * TN * 16 + tn * 16 + lrow;
      cvl[tn] = cvec[col]; bvl[tn] = bias[col];
      w56l[tn][0] = W56g[col * 3];
      w56l[tn][1] = W56g[col * 3 + 1];
      w56l[tn][2] = W56g[col * 3 + 2];
    }
    #pragma unroll
    for (int tm = 0; tm < TM; tm++){
      #pragma unroll
      for (int r = 0; r < 4; r++){
        int lr = wr * TM * 16 + tm * 16 + lq * 4 + r;
        float ws = wsumv[(row0 + lr) >> 5];
        float p0 = 0.f, p1 = 0.f, p2 = 0.f;
        #pragma unroll
        for (int tn = 0; tn < TN; tn++){
          float x = fmaxf(acc[tm][tn][r] + ws * cvl[tn] + bvl[tn], 0.f);
          p0 += x * w56l[tn][0]; p1 += x * w56l[tn][1]; p2 += x * w56l[tn][2];
        }
        #pragma unroll
        for (int off = 8; off; off >>= 1){
          p0 += __shfl_down(p0, off);
          p1 += __shfl_down(p1, off);
          p2 += __shfl_down(p2, off);
        }
        if (lrow == 0){
          atomicAdd(&h5s[lr * 3 + 0], p0);
          atomicAdd(&h5s[lr * 3 + 1], p1);
          atomicAdd(&h5s[lr * 3 + 2], p2);
        }
      }
    }
    __syncthreads();
    float* dst = h5p + (size_t)blockIdx.y * ((size_t)M_ * 3) + (size_t)row0 * 3;
    for (int i = tid; i < BM * 3; i += NT) dst[i] = h5s[i];
  } else {
    #pragma unroll
    for (int tm = 0; tm < TM; tm++){
      #pragma unroll
      for (int tn = 0; tn < TN; tn++){
        int col = col0 + wc * TN * 16 + tn * 16 + lrow;
        float cv = 0.f, bv = 0.f;
        if (cvec){ cv = cvec[col]; bv = bias[col]; }
        #pragma unroll
        for (int r = 0; r < 4; r++){
          int row = row0 + wr * TM * 16 + tm * 16 + lq * 4 + r;
          float x = acc[tm][tn][r];
          if (cvec) x += wsumv[row >> 5] * cv + bv;
          if (relu) x = fmaxf(x, 0.f);
          Hg[(size_t)row * N + col] = f2bf(x);
        }
      }
    }
  }
}

// ---------------- k_xa2: sum 4 H5 partials, per-batch A^2 on F=3 + epilogue ----------------
__global__ __launch_bounds__(1024) void k_xa2(
    const float* __restrict__ h5p, const int* __restrict__ rowptr,
    const int* __restrict__ cols, const float* __restrict__ vals,
    const float* __restrict__ selfw, const float* __restrict__ wsum,
    const float* __restrict__ C56, const float* __restrict__ b6,
    float* __restrict__ XF){
  __shared__ float xs[V_ * 3];
  __shared__ float ys[V_ * 3];
  int b = blockIdx.x, t = threadIdx.x;
  const size_t M3 = (size_t)M_ * 3;
  for (int i = t; i < V_ * 3; i += 1024){
    int v = i / 3, j = i - v * 3;
    size_t g = ((size_t)v * 32 + b) * 3 + j;
    xs[i] = h5p[g] + h5p[M3 + g] + h5p[2 * M3 + g] + h5p[3 * M3 + g];
  }
  __syncthreads();
  for (int v = t; v < V_; v += 1024){
    float sw = selfw[v];
    float a0 = sw * xs[v*3], a1 = sw * xs[v*3+1], a2 = sw * xs[v*3+2];
    int re = rowptr[v + 1];
    for (int e = rowptr[v]; e < re; e++){
      int s = cols[e]; float vv = vals[e];
      a0 += vv * xs[s*3]; a1 += vv * xs[s*3+1]; a2 += vv * xs[s*3+2];
    }
    ys[v*3] = a0; ys[v*3+1] = a1; ys[v*3+2] = a2;
  }
  __syncthreads();
  float* ob = XF + (size_t)b * V_ * 3;
  for (int v = t; v < V_; v += 1024){
    float sw = selfw[v];
    float a0 = sw * ys[v*3], a1 = sw * ys[v*3+1], a2 = sw * ys[v*3+2];
    int re = rowptr[v + 1];
    for (int e = rowptr[v]; e < re; e++){
      int s = cols[e]; float vv = vals[e];
      a0 += vv * ys[s*3]; a1 += vv * ys[s*3+1]; a2 += vv * ys[s*3+2];
    }
    float w = wsum[v];
    a0 = fmaxf(a0 + w * C56[0] + b6[0], 0.f);
    a1 = fmaxf(a1 + w * C56[1] + b6[1], 0.f);
    a2 = fmaxf(a2 + w * C56[2] + b6[2], 0.f);
    ob[v*3] = a0; ob[v*3+1] = a1; ob[v*3+2] = a2;
  }
}

// ---------------- FC split-K stage A ----------------
template<int R, int KC>
__global__ __launch_bounds__(256) void k_fcp(
    const float* __restrict__ in, const float* __restrict__ W,
    float* __restrict__ partial, int K, int N){
  const int n = blockIdx.x * 256 + threadIdx.x;
  const int k0 = blockIdx.y * KC;
  float acc[R] = {};
  for (int kk = 0; kk < KC; kk += 4){
    const float* wp = W + (size_t)(k0 + kk) * N + n;
    float w0 = wp[0];
    float w1 = wp[(size_t)N];
    float w2 = wp[(size_t)2 * N];
    float w3 = wp[(size_t)3 * N];
    #pragma unroll
    for (int r = 0; r < R; r++){
      const float* xp = in + (size_t)r * K + k0 + kk;
      acc[r] += xp[0]*w0 + xp[1]*w1 + xp[2]*w2 + xp[3]*w3;
    }
  }
  float* p = partial + (size_t)blockIdx.y * R * N + n;
  #pragma unroll
  for (int r = 0; r < R; r++) p[(size_t)r * N] = acc[r];
}

// ---------------- FC split-K stage B ----------------
__global__ __launch_bounds__(256) void k_fcr(
    const float* __restrict__ partial, const float* __restrict__ bias,
    float* __restrict__ out, int total, int N, int KS, int mode,
    const float* __restrict__ vert){
  int id = blockIdx.x * 256 + threadIdx.x;
  if (id >= total) return;
  int n = id % N;
  float a0 = 0.f, a1 = 0.f, a2 = 0.f, a3 = 0.f;
  int s = 0;
  for (; s + 4 <= KS; s += 4){
    a0 += partial[(size_t)s * total + id];
    a1 += partial[(size_t)(s + 1) * total + id];
    a2 += partial[(size_t)(s + 2) * total + id];
    a3 += partial[(size_t)(s + 3) * total + id];
  }
  for (; s < KS; s++) a0 += partial[(size_t)s * total + id];
  float acc = a0 + a1 + a2 + a3;
  if (bias) acc += bias[n];
  if (mode) acc = vert[id] + 0.1f * tanhf(acc);
  out[id] = acc;
}

// ---------------- workspace layout ----------------
static constexpr size_t AL(size_t x){ return (x + 255) & ~(size_t)255; }
static constexpr size_t S512 = (size_t)M_ * 512 * 2;
static constexpr size_t S3   = (size_t)M_ * 3 * 4;
static constexpr size_t OXA  = 0;
static constexpr size_t OXB  = OXA  + AL(S512);
static constexpr size_t OVA2 = OXB  + AL(S512);
static constexpr size_t OH5P = OVA2 + AL(S3);
static constexpr size_t OXF  = OH5P + AL(4 * S3);
static constexpr size_t OFC1 = OXF  + AL(S3);
static constexpr size_t OFC2 = OFC1 + AL((size_t)B_ * 1024 * 4);
static constexpr size_t OI1  = OFC2 + AL((size_t)B_ * 1024 * 4);
static constexpr size_t OP   = OI1  + AL((size_t)32 * 512 * 4);
static constexpr size_t OC34 = OP   + AL((size_t)36 * 512 * 4);
static constexpr size_t OW56 = OC34 + AL((size_t)512 * 4);
static constexpr size_t OC56 = OW56 + AL((size_t)512 * 3 * 4);
static constexpr size_t OW3B = OC56 + AL((size_t)3 * 4);
static constexpr size_t OW4T = OW3B + AL((size_t)512 * 512 * 2);
static constexpr size_t OW34 = OW4T + AL((size_t)512 * 512 * 2);
static constexpr size_t OROW = OW34 + AL((size_t)512 * 512 * 2);
static constexpr size_t OCOL = OROW + AL((size_t)(V_ + 1) * 4);
static constexpr size_t OVAL = OCOL + AL((size_t)E_ * 4);
static constexpr size_t OSELF= OVAL + AL((size_t)E_ * 4);
static constexpr size_t OWS  = OSELF+ AL((size_t)V_ * 4);
static constexpr size_t OW2S = OWS  + AL((size_t)V_ * 4);

extern "C" void kernel_launch(void* const* d_in, const int* in_sizes, int n_in,
                              void* d_out, int out_size, void* d_ws, size_t ws_size,
                              hipStream_t stream){
  const float* vert  = (const float*)d_in[0];
  const float* img   = (const float*)d_in[1];
  const int*   ei    = (const int*)  d_in[2];
  const float* W1 = (const float*)d_in[3],  *b1 = (const float*)d_in[4];
  const float* W2 = (const float*)d_in[5],  *b2 = (const float*)d_in[6];
  const float* W3 = (const float*)d_in[7],  *b3 = (const float*)d_in[8];
  const float* W4 = (const float*)d_in[9],  *b4 = (const float*)d_in[10];
  const float* W5 = (const float*)d_in[11], *b5 = (const float*)d_in[12];
  const float* W6 = (const float*)d_in[13], *b6 = (const float*)d_in[14];
  const float* fcW1 = (const float*)d_in[15], *fcb1 = (const float*)d_in[16];
  const float* fcW2 = (const float*)d_in[17], *fcb2 = (const float*)d_in[18];
  const float* fcW3 = (const float*)d_in[19], *fcb3 = (const float*)d_in[20];
  float* out = (float*)d_out;

  char* ws = (char*)d_ws;
  unsigned short* XA  = (unsigned short*)(ws + OXA);
  unsigned short* XB  = (unsigned short*)(ws + OXB);
  float* VA2v = (float*)(ws + OVA2);
  float* H5P  = (float*)(ws + OH5P);
  float* XF   = (float*)(ws + OXF);
  float* FC1o = (float*)(ws + OFC1);
  float* FC2o = (float*)(ws + OFC2);
  float* I1   = (float*)(ws + OI1);
  float* P    = (float*)(ws + OP);
  float* C34  = (float*)(ws + OC34);
  float* W56  = (float*)(ws + OW56);
  float* C56  = (float*)(ws + OC56);
  unsigned short* W3B = (unsigned short*)(ws + OW3B);
  unsigned short* W4T = (unsigned short*)(ws + OW4T);
  unsigned short* W34 = (unsigned short*)(ws + OW34);
  float* PARTA = (float*)(ws + OXA);
  float* PARTB = (float*)(ws + OXB);
  int*   ROW  = (int*)(ws + OROW);
  int*   COL  = (int*)(ws + OCOL);
  float* VAL  = (float*)(ws + OVAL);
  float* SELF = (float*)(ws + OSELF);
  float* WSUM = (float*)(ws + OWS);
  float* W2S  = (float*)(ws + OW2S);

  // ---- CSR (block 0) + preA (blocks 1..324), fused ----
  k_pre0<<<325, 1024, 0, stream>>>(ei, ROW, COL, VAL, SELF, WSUM, W2S,
                                   W3, W4, img, W1, W3B, W4T, PARTB);
  k_preB<<<64 + 9, 256, 0, stream>>>(PARTB, I1, b3, W4, W5, W6, b5, C34, W56, C56);
  k_preC<<<16, 256, 0, stream>>>(b1, W1, I1, W2, PARTB);
  k_preD<<<72, 256, 0, stream>>>(PARTB, P);
  k_gemm<64,64,2,2,2,2><<<dim3(8, 8), 256, 0, stream>>>(W4T, W3B, W34, 512, 512,
                                                        nullptr, nullptr, nullptr, 0,
                                                        nullptr, nullptr);

  // ---- layers 1-3a: VA2 (vertex-major), then fused x2+A-hop ----
  k_va2<<<B_, 1024, 0, stream>>>(vert, ROW, COL, VAL, SELF, VA2v);
  k_y1<<<dim3(V_, 8), 256, 0, stream>>>(VA2v, P, WSUM, W2S, b2, ROW, COL, VAL, SELF, XB);

  // ---- second A-hop + GEMM w/ fused epilogue AND fused W56 contraction ----
  k_aggb<<<dim3(V_, 8), 256, 0, stream>>>(XB, ROW, COL, VAL, SELF, XA);
  k_gemm<128,128,2,2,4,4><<<dim3(M_ / 128, 4), 256, 0, stream>>>(XA, W34, XB, 512, 512,
                                                                 WSUM, C34, b4, 1,
                                                                 W56, H5P);

  // ---- layers 5+6 tail: sum partials + per-batch A^2 (F=3) + epilogue ----
  k_xa2<<<B_, 1024, 0, stream>>>(H5P, ROW, COL, VAL, SELF, WSUM, C56, b6, XF);

  // ---- FC head ----
  k_fcp<32,64><<<dim3(4, 96), 256, 0, stream>>>(XF, fcW1, PARTA, 6144, 1024);
  k_fcr<<<(B_ * 1024 + 255) / 256, 256, 0, stream>>>(PARTA, fcb1, FC1o, 32 * 1024, 1024, 96, 0, nullptr);
  k_fcp<32,64><<<dim3(4, 16), 256, 0, stream>>>(FC1o, fcW2, PARTA, 1024, 1024);
  k_fcr<<<(B_ * 1024 + 255) / 256, 256, 0, stream>>>(PARTA, fcb2, FC2o, 32 * 1024, 1024, 16, 0, nullptr);
  k_fcp<32,64><<<dim3(24, 16), 256, 0, stream>>>(FC2o, fcW3, PARTA, 1024, 6144);
  k_fcr<<<(B_ * 6144 + 255) / 256, 256, 0, stream>>>(PARTA, fcb3, out, 32 * 6144, 6144, 16, 1, vert);
}